// Round 1
// baseline (3042.072 us; speedup 1.0000x reference)
//
#include <hip/hip_runtime.h>
#include <hip/hip_bf16.h>
#include <math.h>

// Problem constants
static constexpr int Bc   = 32;
static constexpr int Nc   = 4096;
static constexpr int Dc   = 256;
static constexpr int NSc  = 8;
static constexpr int HIDc = 128;
static constexpr int ITERSc = 3;
#define EPSf 1e-8f
#define LN_EPSf 1e-5f

__device__ __forceinline__ float bf2f(unsigned int u) {
  return __uint_as_float((u & 0xffffu) << 16);
}

__device__ __forceinline__ void bf8_to_f(uint4 r, float* o) {
  o[0] = bf2f(r.x); o[1] = bf2f(r.x >> 16);
  o[2] = bf2f(r.y); o[3] = bf2f(r.y >> 16);
  o[4] = bf2f(r.z); o[5] = bf2f(r.z >> 16);
  o[6] = bf2f(r.w); o[7] = bf2f(r.w >> 16);
}

// block of 256 threads = 4 waves
__device__ __forceinline__ float block_sum(float v, float* tmp) {
  #pragma unroll
  for (int o = 32; o > 0; o >>= 1) v += __shfl_down(v, o, 64);
  int lane = threadIdx.x & 63, wid = threadIdx.x >> 6;
  __syncthreads();
  if (lane == 0) tmp[wid] = v;
  __syncthreads();
  return tmp[0] + tmp[1] + tmp[2] + tmp[3];
}

// slots = mu + noise * exp(sigma); 65536 elements
__global__ __launch_bounds__(256) void k_init_slots(const float* __restrict__ noise,
                                                    const float* __restrict__ mu,
                                                    const float* __restrict__ sigma,
                                                    float* __restrict__ slots) {
  int idx = blockIdx.x * 256 + threadIdx.x;
  int d = idx & (Dc - 1);
  slots[idx] = mu[d] + noise[idx] * expf(sigma[d]);
}

// LN(inputs) rows + K/V projection, 8 rows per block, bf16 outputs
#define TRr 8
__global__ __launch_bounds__(256) void k_ln_kv(const float* __restrict__ inp,
                                               const float* __restrict__ Wk,
                                               const float* __restrict__ Wv,
                                               const float* __restrict__ g,
                                               const float* __restrict__ bb_,
                                               __hip_bfloat16* __restrict__ kbuf,
                                               __hip_bfloat16* __restrict__ vbuf) {
  __shared__ float xs[TRr][Dc];
  __shared__ float tmp[4];
  int t = threadIdx.x;
  size_t row0 = (size_t)blockIdx.x * TRr;
  float gg = g[t], bb = bb_[t];
  for (int r = 0; r < TRr; r++) {
    float x = inp[(row0 + r) * Dc + t];
    float s = block_sum(x, tmp);
    float m = s * (1.0f / Dc);
    float dx = x - m;
    float s2 = block_sum(dx * dx, tmp);
    float rs = rsqrtf(s2 * (1.0f / Dc) + LN_EPSf);
    xs[r][t] = dx * rs * gg + bb;
  }
  __syncthreads();
  float ak[TRr], av[TRr];
  #pragma unroll
  for (int r = 0; r < TRr; r++) { ak[r] = 0.f; av[r] = 0.f; }
  const float4* wk4 = (const float4*)(Wk + t * Dc);
  const float4* wv4 = (const float4*)(Wv + t * Dc);
  for (int d4 = 0; d4 < Dc / 4; d4++) {
    float4 wk = wk4[d4], wv = wv4[d4];
    #pragma unroll
    for (int r = 0; r < TRr; r++) {
      float4 x = *(const float4*)&xs[r][d4 * 4];
      ak[r] += wk.x * x.x + wk.y * x.y + wk.z * x.z + wk.w * x.w;
      av[r] += wv.x * x.x + wv.y * x.y + wv.z * x.z + wv.w * x.w;
    }
  }
  #pragma unroll
  for (int r = 0; r < TRr; r++) {
    kbuf[(row0 + r) * Dc + t] = __float2bfloat16(ak[r]);
    vbuf[(row0 + r) * Dc + t] = __float2bfloat16(av[r]);
  }
}

// q = LN(slots) @ Wq^T  (one block per slot row); block 0 also zeroes S
__global__ __launch_bounds__(256) void k_qproj(const float* __restrict__ slots,
                                               const float* __restrict__ Wq,
                                               const float* __restrict__ g,
                                               const float* __restrict__ bb_,
                                               float* __restrict__ q,
                                               float* __restrict__ S) {
  __shared__ float xs[Dc];
  __shared__ float tmp[4];
  int t = threadIdx.x;
  int row = blockIdx.x;
  if (blockIdx.x == 0) S[t] = 0.f;
  float x = slots[row * Dc + t];
  float s = block_sum(x, tmp);
  float m = s * (1.0f / Dc);
  float dx = x - m;
  float s2 = block_sum(dx * dx, tmp);
  float rs = rsqrtf(s2 * (1.0f / Dc) + LN_EPSf);
  xs[t] = dx * rs * g[t] + bb_[t];
  __syncthreads();
  float acc = 0.f;
  const float4* wq4 = (const float4*)(Wq + t * Dc);
  for (int d4 = 0; d4 < Dc / 4; d4++) {
    float4 w = wq4[d4];
    float4 x4 = *(const float4*)&xs[d4 * 4];
    acc += w.x * x4.x + w.y * x4.y + w.z * x4.z + w.w * x4.w;
  }
  q[row * Dc + t] = acc;
}

// dots + softmax over slots axis + EPS; writes attn to d_out section, accumulates S[b,i]
// grid: 32 b * 8 jtiles; each thread handles 2 tokens
__global__ __launch_bounds__(256) void k_dots(const float* __restrict__ q,
                                              const __hip_bfloat16* __restrict__ kbuf,
                                              float* __restrict__ attn,
                                              float* __restrict__ S) {
  __shared__ float qs[NSc][Dc];
  __shared__ float tmp[4];
  int t = threadIdx.x;
  int b = blockIdx.x >> 3;
  int jt = blockIdx.x & 7;
  for (int x = t; x < NSc * Dc; x += 256) qs[x >> 8][x & 255] = q[b * NSc * Dc + x];
  __syncthreads();
  int jA = jt * 512 + t;
  const unsigned short* k0 = (const unsigned short*)kbuf + ((size_t)b * Nc + jA) * Dc;
  const unsigned short* k1 = k0 + (size_t)256 * Dc;
  float dot[2][NSc];
  #pragma unroll
  for (int jj = 0; jj < 2; jj++)
    #pragma unroll
    for (int i = 0; i < NSc; i++) dot[jj][i] = 0.f;
  for (int d8 = 0; d8 < Dc / 8; d8++) {
    float kv0[8], kv1[8];
    bf8_to_f(*(const uint4*)(k0 + d8 * 8), kv0);
    bf8_to_f(*(const uint4*)(k1 + d8 * 8), kv1);
    #pragma unroll
    for (int i = 0; i < NSc; i++) {
      const float* qr = &qs[i][d8 * 8];
      float s0 = 0.f, s1 = 0.f;
      #pragma unroll
      for (int u = 0; u < 8; u++) { s0 += kv0[u] * qr[u]; s1 += kv1[u] * qr[u]; }
      dot[0][i] += s0; dot[1][i] += s1;
    }
  }
  float a[2][NSc];
  #pragma unroll
  for (int jj = 0; jj < 2; jj++) {
    float m = -1e30f;
    #pragma unroll
    for (int i = 0; i < NSc; i++) { float s = dot[jj][i] * 0.0625f; dot[jj][i] = s; m = fmaxf(m, s); }
    float sum = 0.f;
    #pragma unroll
    for (int i = 0; i < NSc; i++) { float e = expf(dot[jj][i] - m); a[jj][i] = e; sum += e; }
    float inv = 1.f / sum;
    #pragma unroll
    for (int i = 0; i < NSc; i++) a[jj][i] = a[jj][i] * inv + EPSf;
  }
  float* ab = attn + (size_t)b * NSc * Nc;
  #pragma unroll
  for (int i = 0; i < NSc; i++) {
    ab[i * Nc + jA] = a[0][i];
    ab[i * Nc + jA + 256] = a[1][i];
  }
  for (int i = 0; i < NSc; i++) {
    float bs = block_sum(a[0][i] + a[1][i], tmp);
    if (t == 0) atomicAdd(&S[b * NSc + i], bs);
  }
}

// partial updates: grid 32 b * 8 j-chunks of 512; thread = d
__global__ __launch_bounds__(256) void k_upd_part(const __hip_bfloat16* __restrict__ vbuf,
                                                  const float* __restrict__ attn,
                                                  float* __restrict__ part) {
  __shared__ float at[NSc][512];
  int t = threadIdx.x;
  int b = blockIdx.x >> 3;
  int c = blockIdx.x & 7;
  const float* ab = attn + (size_t)b * NSc * Nc + c * 512;
  for (int x = t; x < NSc * 512; x += 256) at[x >> 9][x & 511] = ab[(x >> 9) * Nc + (x & 511)];
  __syncthreads();
  float acc[NSc];
  #pragma unroll
  for (int i = 0; i < NSc; i++) acc[i] = 0.f;
  const unsigned short* vr = (const unsigned short*)vbuf + ((size_t)b * Nc + c * 512) * Dc + t;
  for (int j4 = 0; j4 < 512; j4 += 4) {
    float vv[4];
    #pragma unroll
    for (int u = 0; u < 4; u++) vv[u] = bf2f(vr[(size_t)(j4 + u) * Dc]);
    #pragma unroll
    for (int i = 0; i < NSc; i++) {
      float4 av = *(const float4*)&at[i][j4];
      acc[i] += av.x * vv[0] + av.y * vv[1] + av.z * vv[2] + av.w * vv[3];
    }
  }
  float* pb = part + ((size_t)(b * 8 + c) * NSc) * Dc + t;
  #pragma unroll
  for (int i = 0; i < NSc; i++) pb[i * Dc] = acc[i];
}

// reduce partials, divide by S
__global__ __launch_bounds__(256) void k_upd_red(const float* __restrict__ part,
                                                 const float* __restrict__ S,
                                                 float* __restrict__ upd) {
  int t = threadIdx.x;
  int b = blockIdx.x >> 3, i = blockIdx.x & 7;
  float s = 0.f;
  for (int c = 0; c < 8; c++) s += part[((size_t)(b * 8 + c) * NSc + i) * Dc + t];
  upd[(b * NSc + i) * Dc + t] = s / S[b * NSc + i];
}

// relational message per batch (one block per b)
__global__ __launch_bounds__(256) void k_rel(const float* __restrict__ slots,
                                             const float* __restrict__ w1,
                                             const float* __restrict__ b1,
                                             const float* __restrict__ w2,
                                             const float* __restrict__ b2,
                                             float* __restrict__ rel) {
  __shared__ float sl[NSc][Dc];
  __shared__ float xa[NSc][HIDc];
  __shared__ float xb[NSc][HIDc];
  __shared__ float hs[NSc][HIDc];
  int t = threadIdx.x;
  int b = blockIdx.x;
  for (int i = 0; i < NSc; i++) sl[i][t] = slots[(b * NSc + i) * Dc + t];
  __syncthreads();
  int h = t & 127;
  int half = t >> 7;  // 0 -> A part, 1 -> B part
  {
    const float* wrow = w1 + h * (2 * Dc) + half * Dc;
    float acc[NSc];
    #pragma unroll
    for (int i = 0; i < NSc; i++) acc[i] = 0.f;
    for (int d4 = 0; d4 < Dc / 4; d4++) {
      float4 w = *(const float4*)(wrow + d4 * 4);
      #pragma unroll
      for (int i = 0; i < NSc; i++) {
        const float* s4 = &sl[i][d4 * 4];
        acc[i] += w.x * s4[0] + w.y * s4[1] + w.z * s4[2] + w.w * s4[3];
      }
    }
    float* dst = half ? &xb[0][0] : &xa[0][0];
    #pragma unroll
    for (int i = 0; i < NSc; i++) dst[i * HIDc + h] = acc[i];
  }
  __syncthreads();
  {
    float bv = b1[h];
    int i0 = half * 4;
    for (int ii = 0; ii < 4; ii++) {
      int i = i0 + ii;
      float av = xa[i][h];
      float s = 0.f;
      #pragma unroll
      for (int j = 0; j < NSc; j++) {
        if (j == i) continue;
        float x = av + xb[j][h] + bv;
        s += fmaxf(x, 0.f);
      }
      hs[i][h] = s;
    }
  }
  __syncthreads();
  {
    float acc[NSc];
    #pragma unroll
    for (int i = 0; i < NSc; i++) acc[i] = 0.f;
    const float* wrow = w2 + t * HIDc;
    for (int h4 = 0; h4 < HIDc / 4; h4++) {
      float4 w = *(const float4*)(wrow + h4 * 4);
      #pragma unroll
      for (int i = 0; i < NSc; i++) {
        const float* hh = &hs[i][h4 * 4];
        acc[i] += w.x * hh[0] + w.y * hh[1] + w.z * hh[2] + w.w * hh[3];
      }
    }
    float bv = b2[t];
    #pragma unroll
    for (int i = 0; i < NSc; i++) rel[(b * NSc + i) * Dc + t] = acc[i] * (1.0f / (NSc - 1)) + bv;
  }
}

// GRU cell + FF residual, one block per slot row; in-place slots update
__global__ __launch_bounds__(256) void k_gru_ff(const float* __restrict__ upd,
                                                const float* __restrict__ rel,
                                                float* __restrict__ slots,
                                                const float* __restrict__ w_ih,
                                                const float* __restrict__ w_hh,
                                                const float* __restrict__ b_ih,
                                                const float* __restrict__ b_hh,
                                                const float* __restrict__ ow1,
                                                const float* __restrict__ ob1,
                                                const float* __restrict__ ow2,
                                                const float* __restrict__ ob2,
                                                const float* __restrict__ lng,
                                                const float* __restrict__ lnb,
                                                float* __restrict__ out_final,
                                                int write_final) {
  __shared__ float gin[2 * Dc];
  __shared__ float hh[Dc];
  __shared__ float ff[Dc];
  __shared__ float h1[HIDc];
  __shared__ float tmp[4];
  int t = threadIdx.x;
  int row = blockIdx.x;
  gin[t] = upd[row * Dc + t];
  gin[Dc + t] = rel[row * Dc + t];
  float hv = slots[row * Dc + t];
  hh[t] = hv;
  __syncthreads();
  float gx[3], gh[3];
  #pragma unroll
  for (int gi = 0; gi < 3; gi++) {
    int orow = gi * Dc + t;
    float acc = 0.f;
    const float* wrow = w_ih + (size_t)orow * (2 * Dc);
    for (int c4 = 0; c4 < (2 * Dc) / 4; c4++) {
      float4 w = *(const float4*)(wrow + c4 * 4);
      const float* g4 = &gin[c4 * 4];
      acc += w.x * g4[0] + w.y * g4[1] + w.z * g4[2] + w.w * g4[3];
    }
    gx[gi] = acc + b_ih[orow];
    float acc2 = 0.f;
    const float* wrow2 = w_hh + (size_t)orow * Dc;
    for (int c4 = 0; c4 < Dc / 4; c4++) {
      float4 w = *(const float4*)(wrow2 + c4 * 4);
      const float* h4 = &hh[c4 * 4];
      acc2 += w.x * h4[0] + w.y * h4[1] + w.z * h4[2] + w.w * h4[3];
    }
    gh[gi] = acc2 + b_hh[orow];
  }
  float r = 1.f / (1.f + expf(-(gx[0] + gh[0])));
  float z = 1.f / (1.f + expf(-(gx[1] + gh[1])));
  float n = tanhf(gx[2] + r * gh[2]);
  float snew = (1.f - z) * n + z * hv;
  // FF layernorm
  float s = block_sum(snew, tmp);
  float m = s * (1.0f / Dc);
  float dx = snew - m;
  float s2 = block_sum(dx * dx, tmp);
  float rs = rsqrtf(s2 * (1.0f / Dc) + LN_EPSf);
  ff[t] = dx * rs * lng[t] + lnb[t];
  __syncthreads();
  if (t < HIDc) {
    float acc = 0.f;
    const float* wrow = ow1 + t * Dc;
    for (int c4 = 0; c4 < Dc / 4; c4++) {
      float4 w = *(const float4*)(wrow + c4 * 4);
      const float* f4 = &ff[c4 * 4];
      acc += w.x * f4[0] + w.y * f4[1] + w.z * f4[2] + w.w * f4[3];
    }
    h1[t] = fmaxf(acc + ob1[t], 0.f);
  }
  __syncthreads();
  float acc = 0.f;
  const float* wrow = ow2 + t * HIDc;
  for (int c4 = 0; c4 < HIDc / 4; c4++) {
    float4 w = *(const float4*)(wrow + c4 * 4);
    const float* h4 = &h1[c4 * 4];
    acc += w.x * h4[0] + w.y * h4[1] + w.z * h4[2] + w.w * h4[3];
  }
  float res = snew + acc + ob2[t];
  slots[row * Dc + t] = res;
  if (write_final) out_final[row * Dc + t] = res;
}

extern "C" void kernel_launch(void* const* d_in, const int* in_sizes, int n_in,
                              void* d_out, int out_size, void* d_ws, size_t ws_size,
                              hipStream_t stream) {
  const float* inputs      = (const float*)d_in[0];
  const float* slot_noise  = (const float*)d_in[1];
  const float* slots_mu    = (const float*)d_in[2];
  const float* slots_sigma = (const float*)d_in[3];
  const float* Wq          = (const float*)d_in[4];
  const float* Wk          = (const float*)d_in[5];
  const float* Wv          = (const float*)d_in[6];
  const float* gru_w_ih    = (const float*)d_in[7];
  const float* gru_w_hh    = (const float*)d_in[8];
  const float* gru_b_ih    = (const float*)d_in[9];
  const float* gru_b_hh    = (const float*)d_in[10];
  const float* obj_w1      = (const float*)d_in[11];
  const float* obj_b1      = (const float*)d_in[12];
  const float* obj_w2      = (const float*)d_in[13];
  const float* obj_b2      = (const float*)d_in[14];
  const float* rel_w1      = (const float*)d_in[15];
  const float* rel_b1      = (const float*)d_in[16];
  const float* rel_w2      = (const float*)d_in[17];
  const float* rel_b2      = (const float*)d_in[18];
  const float* ln_in_g     = (const float*)d_in[19];
  const float* ln_in_b     = (const float*)d_in[20];
  const float* ln_s_g      = (const float*)d_in[21];
  const float* ln_s_b      = (const float*)d_in[22];
  const float* ln_ff_g     = (const float*)d_in[23];
  const float* ln_ff_b     = (const float*)d_in[24];

  // workspace layout (bytes):
  //   k bf16:   0          .. 67108864
  //   v bf16:   67108864   .. 134217728
  //   q f32:    134217728  (+262144)
  //   slots:    134479872  (+262144)
  //   upd:      134742016  (+262144)
  //   rel:      135004160  (+262144)
  //   S:        135266304  (+1024)
  //   part:     135267328  (+2097152)  -> total 137364480
  char* w = (char*)d_ws;
  __hip_bfloat16* kbuf = (__hip_bfloat16*)(w);
  __hip_bfloat16* vbuf = (__hip_bfloat16*)(w + (size_t)67108864);
  float* qbuf  = (float*)(w + (size_t)134217728);
  float* slots = (float*)(w + (size_t)134479872);
  float* upd   = (float*)(w + (size_t)134742016);
  float* relb  = (float*)(w + (size_t)135004160);
  float* Sbuf  = (float*)(w + (size_t)135266304);
  float* part  = (float*)(w + (size_t)135267328);

  float* out = (float*)d_out;
  float* attn_base = out + (size_t)Bc * NSc * Dc;  // slots occupy first 65536 floats

  k_init_slots<<<Bc * NSc * Dc / 256, 256, 0, stream>>>(slot_noise, slots_mu, slots_sigma, slots);
  k_ln_kv<<<Bc * Nc / TRr, 256, 0, stream>>>(inputs, Wk, Wv, ln_in_g, ln_in_b, kbuf, vbuf);

  for (int it = 0; it < ITERSc; it++) {
    float* attn = attn_base + (size_t)it * Bc * NSc * Nc;
    k_qproj<<<Bc * NSc, 256, 0, stream>>>(slots, Wq, ln_s_g, ln_s_b, qbuf, Sbuf);
    k_dots<<<Bc * 8, 256, 0, stream>>>(qbuf, kbuf, attn, Sbuf);
    k_upd_part<<<Bc * 8, 256, 0, stream>>>(vbuf, attn, part);
    k_upd_red<<<Bc * NSc, 256, 0, stream>>>(part, Sbuf, upd);
    k_rel<<<Bc, 256, 0, stream>>>(slots, rel_w1, rel_b1, rel_w2, rel_b2, relb);
    k_gru_ff<<<Bc * NSc, 256, 0, stream>>>(upd, relb, slots,
                                           gru_w_ih, gru_w_hh, gru_b_ih, gru_b_hh,
                                           obj_w1, obj_b1, obj_w2, obj_b2,
                                           ln_ff_g, ln_ff_b,
                                           out, it == ITERSc - 1 ? 1 : 0);
  }
}

// Round 2
// 1281.382 us; speedup vs baseline: 2.3741x; 2.3741x over previous
//
#include <hip/hip_runtime.h>
#include <hip/hip_bf16.h>
#include <math.h>

// Problem constants
static constexpr int Bc   = 32;
static constexpr int Nc   = 4096;
static constexpr int Dc   = 256;
static constexpr int NSc  = 8;
static constexpr int HIDc = 128;
static constexpr int ITERSc = 3;
#define EPSf 1e-8f
#define LN_EPSf 1e-5f

typedef __attribute__((ext_vector_type(8))) short bf16x8;
typedef __attribute__((ext_vector_type(8))) unsigned short u16x8;
typedef __attribute__((ext_vector_type(4))) float f32x4;

__device__ __forceinline__ float bf2f(unsigned int u) {
  return __uint_as_float((u & 0xffffu) << 16);
}

__device__ __forceinline__ unsigned short f2bfu(float f) {
  unsigned int u = __float_as_uint(f);
  unsigned int r = (u + 0x7fffu + ((u >> 16) & 1u)) >> 16;
  return (unsigned short)r;
}

__device__ __forceinline__ void bf8_to_f(uint4 r, float* o) {
  o[0] = bf2f(r.x); o[1] = bf2f(r.x >> 16);
  o[2] = bf2f(r.y); o[3] = bf2f(r.y >> 16);
  o[4] = bf2f(r.z); o[5] = bf2f(r.z >> 16);
  o[6] = bf2f(r.w); o[7] = bf2f(r.w >> 16);
}

__device__ __forceinline__ void gl_lds16(const void* g, void* l) {
  __builtin_amdgcn_global_load_lds(
      (__attribute__((address_space(1))) void*)(g),
      (__attribute__((address_space(3))) void*)(l), 16, 0, 0);
}

// block of 256 threads = 4 waves
__device__ __forceinline__ float block_sum(float v, float* tmp) {
  #pragma unroll
  for (int o = 32; o > 0; o >>= 1) v += __shfl_down(v, o, 64);
  int lane = threadIdx.x & 63, wid = threadIdx.x >> 6;
  __syncthreads();
  if (lane == 0) tmp[wid] = v;
  __syncthreads();
  return tmp[0] + tmp[1] + tmp[2] + tmp[3];
}

// slots = mu + noise * exp(sigma); 65536 elements
__global__ __launch_bounds__(256) void k_init_slots(const float* __restrict__ noise,
                                                    const float* __restrict__ mu,
                                                    const float* __restrict__ sigma,
                                                    float* __restrict__ slots) {
  int idx = blockIdx.x * 256 + threadIdx.x;
  int d = idx & (Dc - 1);
  slots[idx] = mu[d] + noise[idx] * expf(sigma[d]);
}

// per-row LN stats (mu, rsigma) for inputs; 8 rows per block
__global__ __launch_bounds__(256) void k_stats(const float* __restrict__ inp,
                                               float2* __restrict__ stats) {
  __shared__ float tmp[4];
  int t = threadIdx.x;
  size_t row0 = (size_t)blockIdx.x * 8;
  for (int r = 0; r < 8; r++) {
    float x = inp[(row0 + r) * Dc + t];
    float s = block_sum(x, tmp);
    float m = s * (1.0f / Dc);
    float dx = x - m;
    float s2 = block_sum(dx * dx, tmp);
    float rs = rsqrtf(s2 * (1.0f / Dc) + LN_EPSf);
    if (t == 0) stats[row0 + r] = make_float2(m, rs);
  }
}

// convert Wk (rows 0..255) and Wv (rows 256..511) to bf16 [512][256]
__global__ __launch_bounds__(256) void k_wcvt(const float* __restrict__ Wk,
                                              const float* __restrict__ Wv,
                                              unsigned short* __restrict__ wbuf) {
  int idx = blockIdx.x * 256 + threadIdx.x;  // 0..131071
  int n = idx >> 8, k = idx & 255;
  float v = (n < 256) ? Wk[n * 256 + k] : Wv[(n - 256) * 256 + k];
  wbuf[idx] = f2bfu(v);
}

// Fused LN + K/V projection as bf16 MFMA GEMM.
// C[M=131072][N=512] = LN(inputs) @ W^T, N cols 0..255 -> kbuf, 256..511 -> vbuf
#define BM 128
#define BN 128
#define BK 64
__global__ __launch_bounds__(256) void k_gemm_kv(const float* __restrict__ inp,
                                                 const float2* __restrict__ stats,
                                                 const float* __restrict__ lng,
                                                 const float* __restrict__ lnb,
                                                 const unsigned short* __restrict__ wbuf,
                                                 unsigned short* __restrict__ kbuf,
                                                 unsigned short* __restrict__ vbuf) {
  __shared__ unsigned short Als[BM * BK];  // xor-swizzled 16B chunks
  __shared__ unsigned short Bls[BN * BK];
  int tid = threadIdx.x;
  int lane = tid & 63, w = tid >> 6;
  int idx16 = lane & 15, quad = lane >> 4;
  int m0 = (blockIdx.x >> 2) * BM;
  int n0 = (blockIdx.x & 3) * BN;
  int wm = w & 1, wn = w >> 1;

  f32x4 acc[4][4];
  #pragma unroll
  for (int i = 0; i < 4; i++)
    #pragma unroll
    for (int j = 0; j < 4; j++) acc[i][j] = (f32x4){0.f, 0.f, 0.f, 0.f};

  for (int kt = 0; kt < 4; kt++) {
    int k0 = kt * BK;
    // ---- stage B via async global->LDS (16B/lane) ----
    #pragma unroll
    for (int c = 0; c < 4; c++) {
      int idx = (w * 4 + c) * 64 + lane;   // 16B chunk index in tile
      int row = idx >> 3, lc = idx & 7;
      int gc = lc ^ (row & 7);
      const char* gsrc = (const char*)wbuf + ((size_t)(n0 + row) * 256 + k0) * 2 + gc * 16;
      char* ldst = (char*)Bls + (size_t)(w * 4 + c) * 1024;
      gl_lds16(gsrc, ldst);
    }
    // ---- stage A: fp32 loads + LN + bf16 pack + ds_write_b128 ----
    #pragma unroll
    for (int p = 0; p < 4; p++) {
      int idx = p * 256 + tid;             // 0..1023, 8-float chunks
      int row = idx >> 3, c8 = idx & 7;
      const float* src = inp + (size_t)(m0 + row) * 256 + k0 + c8 * 8;
      float2 st = stats[m0 + row];
      float4 x0 = *(const float4*)(src);
      float4 x1 = *(const float4*)(src + 4);
      float4 g0 = *(const float4*)(lng + k0 + c8 * 8);
      float4 g1 = *(const float4*)(lng + k0 + c8 * 8 + 4);
      float4 b0 = *(const float4*)(lnb + k0 + c8 * 8);
      float4 b1 = *(const float4*)(lnb + k0 + c8 * 8 + 4);
      u16x8 pk;
      pk[0] = f2bfu((x0.x - st.x) * st.y * g0.x + b0.x);
      pk[1] = f2bfu((x0.y - st.x) * st.y * g0.y + b0.y);
      pk[2] = f2bfu((x0.z - st.x) * st.y * g0.z + b0.z);
      pk[3] = f2bfu((x0.w - st.x) * st.y * g0.w + b0.w);
      pk[4] = f2bfu((x1.x - st.x) * st.y * g1.x + b1.x);
      pk[5] = f2bfu((x1.y - st.x) * st.y * g1.y + b1.y);
      pk[6] = f2bfu((x1.z - st.x) * st.y * g1.z + b1.z);
      pk[7] = f2bfu((x1.w - st.x) * st.y * g1.w + b1.w);
      int dchunk = c8 ^ (row & 7);
      *(u16x8*)((char*)Als + (size_t)(row * 8 + dchunk) * 16) = pk;
    }
    __syncthreads();
    // ---- compute: 2 k-steps x 16 MFMA per wave ----
    #pragma unroll
    for (int ks = 0; ks < 2; ks++) {
      bf16x8 af[4], bfr[4];
      int kchunk = ks * 4 + quad;
      #pragma unroll
      for (int mt = 0; mt < 4; mt++) {
        int row = wm * 64 + mt * 16 + idx16;
        af[mt] = *(const bf16x8*)((const char*)Als + (size_t)(row * 8 + (kchunk ^ (row & 7))) * 16);
      }
      #pragma unroll
      for (int nt = 0; nt < 4; nt++) {
        int row = wn * 64 + nt * 16 + idx16;
        bfr[nt] = *(const bf16x8*)((const char*)Bls + (size_t)(row * 8 + (kchunk ^ (row & 7))) * 16);
      }
      #pragma unroll
      for (int mt = 0; mt < 4; mt++)
        #pragma unroll
        for (int nt = 0; nt < 4; nt++)
          acc[mt][nt] = __builtin_amdgcn_mfma_f32_16x16x32_bf16(af[mt], bfr[nt], acc[mt][nt], 0, 0, 0);
    }
    __syncthreads();
  }
  // ---- epilogue: C/D layout col=lane&15, row=quad*4+reg ----
  unsigned short* dst = (n0 < 256) ? kbuf : vbuf;
  int coff = (n0 < 256) ? n0 : (n0 - 256);
  #pragma unroll
  for (int mt = 0; mt < 4; mt++) {
    #pragma unroll
    for (int nt = 0; nt < 4; nt++) {
      int gm = m0 + wm * 64 + mt * 16 + quad * 4;
      int col = coff + wn * 64 + nt * 16 + idx16;
      #pragma unroll
      for (int r = 0; r < 4; r++)
        dst[(size_t)(gm + r) * 256 + col] = f2bfu(acc[mt][nt][r]);
    }
  }
}

// q = LN(slots) @ Wq^T  (one block per slot row); block 0 also zeroes S
__global__ __launch_bounds__(256) void k_qproj(const float* __restrict__ slots,
                                               const float* __restrict__ Wq,
                                               const float* __restrict__ g,
                                               const float* __restrict__ bb_,
                                               float* __restrict__ q,
                                               float* __restrict__ S) {
  __shared__ float xs[Dc];
  __shared__ float tmp[4];
  int t = threadIdx.x;
  int row = blockIdx.x;
  if (blockIdx.x == 0) S[t] = 0.f;
  float x = slots[row * Dc + t];
  float s = block_sum(x, tmp);
  float m = s * (1.0f / Dc);
  float dx = x - m;
  float s2 = block_sum(dx * dx, tmp);
  float rs = rsqrtf(s2 * (1.0f / Dc) + LN_EPSf);
  xs[t] = dx * rs * g[t] + bb_[t];
  __syncthreads();
  float acc = 0.f;
  const float4* wq4 = (const float4*)(Wq + t * Dc);
  for (int d4 = 0; d4 < Dc / 4; d4++) {
    float4 w = wq4[d4];
    float4 x4 = *(const float4*)&xs[d4 * 4];
    acc += w.x * x4.x + w.y * x4.y + w.z * x4.z + w.w * x4.w;
  }
  q[row * Dc + t] = acc;
}

// dots + softmax over slots axis + EPS; writes attn to d_out section, accumulates S[b,i]
__global__ __launch_bounds__(256) void k_dots(const float* __restrict__ q,
                                              const __hip_bfloat16* __restrict__ kbuf,
                                              float* __restrict__ attn,
                                              float* __restrict__ S) {
  __shared__ float qs[NSc][Dc];
  __shared__ float tmp[4];
  int t = threadIdx.x;
  int b = blockIdx.x >> 3;
  int jt = blockIdx.x & 7;
  for (int x = t; x < NSc * Dc; x += 256) qs[x >> 8][x & 255] = q[b * NSc * Dc + x];
  __syncthreads();
  int jA = jt * 512 + t;
  const unsigned short* k0 = (const unsigned short*)kbuf + ((size_t)b * Nc + jA) * Dc;
  const unsigned short* k1 = k0 + (size_t)256 * Dc;
  float dot[2][NSc];
  #pragma unroll
  for (int jj = 0; jj < 2; jj++)
    #pragma unroll
    for (int i = 0; i < NSc; i++) dot[jj][i] = 0.f;
  for (int d8 = 0; d8 < Dc / 8; d8++) {
    float kv0[8], kv1[8];
    bf8_to_f(*(const uint4*)(k0 + d8 * 8), kv0);
    bf8_to_f(*(const uint4*)(k1 + d8 * 8), kv1);
    #pragma unroll
    for (int i = 0; i < NSc; i++) {
      const float* qr = &qs[i][d8 * 8];
      float s0 = 0.f, s1 = 0.f;
      #pragma unroll
      for (int u = 0; u < 8; u++) { s0 += kv0[u] * qr[u]; s1 += kv1[u] * qr[u]; }
      dot[0][i] += s0; dot[1][i] += s1;
    }
  }
  float a[2][NSc];
  #pragma unroll
  for (int jj = 0; jj < 2; jj++) {
    float m = -1e30f;
    #pragma unroll
    for (int i = 0; i < NSc; i++) { float s = dot[jj][i] * 0.0625f; dot[jj][i] = s; m = fmaxf(m, s); }
    float sum = 0.f;
    #pragma unroll
    for (int i = 0; i < NSc; i++) { float e = expf(dot[jj][i] - m); a[jj][i] = e; sum += e; }
    float inv = 1.f / sum;
    #pragma unroll
    for (int i = 0; i < NSc; i++) a[jj][i] = a[jj][i] * inv + EPSf;
  }
  float* ab = attn + (size_t)b * NSc * Nc;
  #pragma unroll
  for (int i = 0; i < NSc; i++) {
    ab[i * Nc + jA] = a[0][i];
    ab[i * Nc + jA + 256] = a[1][i];
  }
  for (int i = 0; i < NSc; i++) {
    float bs = block_sum(a[0][i] + a[1][i], tmp);
    if (t == 0) atomicAdd(&S[b * NSc + i], bs);
  }
}

// partial updates: grid 32 b * 8 j-chunks of 512; thread = d
__global__ __launch_bounds__(256) void k_upd_part(const __hip_bfloat16* __restrict__ vbuf,
                                                  const float* __restrict__ attn,
                                                  float* __restrict__ part) {
  __shared__ float at[NSc][512];
  int t = threadIdx.x;
  int b = blockIdx.x >> 3;
  int c = blockIdx.x & 7;
  const float* ab = attn + (size_t)b * NSc * Nc + c * 512;
  for (int x = t; x < NSc * 512; x += 256) at[x >> 9][x & 511] = ab[(x >> 9) * Nc + (x & 511)];
  __syncthreads();
  float acc[NSc];
  #pragma unroll
  for (int i = 0; i < NSc; i++) acc[i] = 0.f;
  const unsigned short* vr = (const unsigned short*)vbuf + ((size_t)b * Nc + c * 512) * Dc + t;
  for (int j4 = 0; j4 < 512; j4 += 4) {
    float vv[4];
    #pragma unroll
    for (int u = 0; u < 4; u++) vv[u] = bf2f(vr[(size_t)(j4 + u) * Dc]);
    #pragma unroll
    for (int i = 0; i < NSc; i++) {
      float4 av = *(const float4*)&at[i][j4];
      acc[i] += av.x * vv[0] + av.y * vv[1] + av.z * vv[2] + av.w * vv[3];
    }
  }
  float* pb = part + ((size_t)(b * 8 + c) * NSc) * Dc + t;
  #pragma unroll
  for (int i = 0; i < NSc; i++) pb[i * Dc] = acc[i];
}

// reduce partials, divide by S
__global__ __launch_bounds__(256) void k_upd_red(const float* __restrict__ part,
                                                 const float* __restrict__ S,
                                                 float* __restrict__ upd) {
  int t = threadIdx.x;
  int b = blockIdx.x >> 3, i = blockIdx.x & 7;
  float s = 0.f;
  for (int c = 0; c < 8; c++) s += part[((size_t)(b * 8 + c) * NSc + i) * Dc + t];
  upd[(b * NSc + i) * Dc + t] = s / S[b * NSc + i];
}

// relational message per batch (one block per b)
__global__ __launch_bounds__(256) void k_rel(const float* __restrict__ slots,
                                             const float* __restrict__ w1,
                                             const float* __restrict__ b1,
                                             const float* __restrict__ w2,
                                             const float* __restrict__ b2,
                                             float* __restrict__ rel) {
  __shared__ float sl[NSc][Dc];
  __shared__ float xa[NSc][HIDc];
  __shared__ float xb[NSc][HIDc];
  __shared__ float hs[NSc][HIDc];
  int t = threadIdx.x;
  int b = blockIdx.x;
  for (int i = 0; i < NSc; i++) sl[i][t] = slots[(b * NSc + i) * Dc + t];
  __syncthreads();
  int h = t & 127;
  int half = t >> 7;  // 0 -> A part, 1 -> B part
  {
    const float* wrow = w1 + h * (2 * Dc) + half * Dc;
    float acc[NSc];
    #pragma unroll
    for (int i = 0; i < NSc; i++) acc[i] = 0.f;
    for (int d4 = 0; d4 < Dc / 4; d4++) {
      float4 w = *(const float4*)(wrow + d4 * 4);
      #pragma unroll
      for (int i = 0; i < NSc; i++) {
        const float* s4 = &sl[i][d4 * 4];
        acc[i] += w.x * s4[0] + w.y * s4[1] + w.z * s4[2] + w.w * s4[3];
      }
    }
    float* dst = half ? &xb[0][0] : &xa[0][0];
    #pragma unroll
    for (int i = 0; i < NSc; i++) dst[i * HIDc + h] = acc[i];
  }
  __syncthreads();
  {
    float bv = b1[h];
    int i0 = half * 4;
    for (int ii = 0; ii < 4; ii++) {
      int i = i0 + ii;
      float av = xa[i][h];
      float s = 0.f;
      #pragma unroll
      for (int j = 0; j < NSc; j++) {
        if (j == i) continue;
        float x = av + xb[j][h] + bv;
        s += fmaxf(x, 0.f);
      }
      hs[i][h] = s;
    }
  }
  __syncthreads();
  {
    float acc[NSc];
    #pragma unroll
    for (int i = 0; i < NSc; i++) acc[i] = 0.f;
    const float* wrow = w2 + t * HIDc;
    for (int h4 = 0; h4 < HIDc / 4; h4++) {
      float4 w = *(const float4*)(wrow + h4 * 4);
      #pragma unroll
      for (int i = 0; i < NSc; i++) {
        const float* hh = &hs[i][h4 * 4];
        acc[i] += w.x * hh[0] + w.y * hh[1] + w.z * hh[2] + w.w * hh[3];
      }
    }
    float bv = b2[t];
    #pragma unroll
    for (int i = 0; i < NSc; i++) rel[(b * NSc + i) * Dc + t] = acc[i] * (1.0f / (NSc - 1)) + bv;
  }
}

// GRU cell + FF residual, one block per slot row; in-place slots update
__global__ __launch_bounds__(256) void k_gru_ff(const float* __restrict__ upd,
                                                const float* __restrict__ rel,
                                                float* __restrict__ slots,
                                                const float* __restrict__ w_ih,
                                                const float* __restrict__ w_hh,
                                                const float* __restrict__ b_ih,
                                                const float* __restrict__ b_hh,
                                                const float* __restrict__ ow1,
                                                const float* __restrict__ ob1,
                                                const float* __restrict__ ow2,
                                                const float* __restrict__ ob2,
                                                const float* __restrict__ lng,
                                                const float* __restrict__ lnb,
                                                float* __restrict__ out_final,
                                                int write_final) {
  __shared__ float gin[2 * Dc];
  __shared__ float hh[Dc];
  __shared__ float ff[Dc];
  __shared__ float h1[HIDc];
  __shared__ float tmp[4];
  int t = threadIdx.x;
  int row = blockIdx.x;
  gin[t] = upd[row * Dc + t];
  gin[Dc + t] = rel[row * Dc + t];
  float hv = slots[row * Dc + t];
  hh[t] = hv;
  __syncthreads();
  float gx[3], gh[3];
  #pragma unroll
  for (int gi = 0; gi < 3; gi++) {
    int orow = gi * Dc + t;
    float acc = 0.f;
    const float* wrow = w_ih + (size_t)orow * (2 * Dc);
    for (int c4 = 0; c4 < (2 * Dc) / 4; c4++) {
      float4 w = *(const float4*)(wrow + c4 * 4);
      const float* g4 = &gin[c4 * 4];
      acc += w.x * g4[0] + w.y * g4[1] + w.z * g4[2] + w.w * g4[3];
    }
    gx[gi] = acc + b_ih[orow];
    float acc2 = 0.f;
    const float* wrow2 = w_hh + (size_t)orow * Dc;
    for (int c4 = 0; c4 < Dc / 4; c4++) {
      float4 w = *(const float4*)(wrow2 + c4 * 4);
      const float* h4 = &hh[c4 * 4];
      acc2 += w.x * h4[0] + w.y * h4[1] + w.z * h4[2] + w.w * h4[3];
    }
    gh[gi] = acc2 + b_hh[orow];
  }
  float r = 1.f / (1.f + expf(-(gx[0] + gh[0])));
  float z = 1.f / (1.f + expf(-(gx[1] + gh[1])));
  float n = tanhf(gx[2] + r * gh[2]);
  float snew = (1.f - z) * n + z * hv;
  // FF layernorm
  float s = block_sum(snew, tmp);
  float m = s * (1.0f / Dc);
  float dx = snew - m;
  float s2 = block_sum(dx * dx, tmp);
  float rs = rsqrtf(s2 * (1.0f / Dc) + LN_EPSf);
  ff[t] = dx * rs * lng[t] + lnb[t];
  __syncthreads();
  if (t < HIDc) {
    float acc = 0.f;
    const float* wrow = ow1 + t * Dc;
    for (int c4 = 0; c4 < Dc / 4; c4++) {
      float4 w = *(const float4*)(wrow + c4 * 4);
      const float* f4 = &ff[c4 * 4];
      acc += w.x * f4[0] + w.y * f4[1] + w.z * f4[2] + w.w * f4[3];
    }
    h1[t] = fmaxf(acc + ob1[t], 0.f);
  }
  __syncthreads();
  float acc = 0.f;
  const float* wrow = ow2 + t * HIDc;
  for (int c4 = 0; c4 < HIDc / 4; c4++) {
    float4 w = *(const float4*)(wrow + c4 * 4);
    const float* h4 = &h1[c4 * 4];
    acc += w.x * h4[0] + w.y * h4[1] + w.z * h4[2] + w.w * h4[3];
  }
  float res = snew + acc + ob2[t];
  slots[row * Dc + t] = res;
  if (write_final) out_final[row * Dc + t] = res;
}

extern "C" void kernel_launch(void* const* d_in, const int* in_sizes, int n_in,
                              void* d_out, int out_size, void* d_ws, size_t ws_size,
                              hipStream_t stream) {
  const float* inputs      = (const float*)d_in[0];
  const float* slot_noise  = (const float*)d_in[1];
  const float* slots_mu    = (const float*)d_in[2];
  const float* slots_sigma = (const float*)d_in[3];
  const float* Wq          = (const float*)d_in[4];
  const float* Wk          = (const float*)d_in[5];
  const float* Wv          = (const float*)d_in[6];
  const float* gru_w_ih    = (const float*)d_in[7];
  const float* gru_w_hh    = (const float*)d_in[8];
  const float* gru_b_ih    = (const float*)d_in[9];
  const float* gru_b_hh    = (const float*)d_in[10];
  const float* obj_w1      = (const float*)d_in[11];
  const float* obj_b1      = (const float*)d_in[12];
  const float* obj_w2      = (const float*)d_in[13];
  const float* obj_b2      = (const float*)d_in[14];
  const float* rel_w1      = (const float*)d_in[15];
  const float* rel_b1      = (const float*)d_in[16];
  const float* rel_w2      = (const float*)d_in[17];
  const float* rel_b2      = (const float*)d_in[18];
  const float* ln_in_g     = (const float*)d_in[19];
  const float* ln_in_b     = (const float*)d_in[20];
  const float* ln_s_g      = (const float*)d_in[21];
  const float* ln_s_b      = (const float*)d_in[22];
  const float* ln_ff_g     = (const float*)d_in[23];
  const float* ln_ff_b     = (const float*)d_in[24];

  // workspace layout (bytes):
  //   k bf16:   0          .. 67108864
  //   v bf16:   67108864   .. 134217728
  //   q f32:    134217728  (+262144)
  //   slots:    134479872  (+262144)
  //   upd:      134742016  (+262144)
  //   rel:      135004160  (+262144)
  //   S:        135266304  (+1024)
  //   part:     135267328  (+2097152)  -> total 137364480
  //   stats/wbuf alias the `part` region (dead before first k_upd_part):
  //     stats @135267328 (+1048576), wbuf @136315904 (+262144)
  char* w = (char*)d_ws;
  unsigned short* kbuf = (unsigned short*)(w);
  unsigned short* vbuf = (unsigned short*)(w + (size_t)67108864);
  float* qbuf  = (float*)(w + (size_t)134217728);
  float* slots = (float*)(w + (size_t)134479872);
  float* upd   = (float*)(w + (size_t)134742016);
  float* relb  = (float*)(w + (size_t)135004160);
  float* Sbuf  = (float*)(w + (size_t)135266304);
  float* part  = (float*)(w + (size_t)135267328);
  float2* stats = (float2*)(w + (size_t)135267328);
  unsigned short* wbuf = (unsigned short*)(w + (size_t)136315904);

  float* out = (float*)d_out;
  float* attn_base = out + (size_t)Bc * NSc * Dc;  // slots occupy first 65536 floats

  k_init_slots<<<Bc * NSc * Dc / 256, 256, 0, stream>>>(slot_noise, slots_mu, slots_sigma, slots);
  k_stats<<<Bc * Nc / 8, 256, 0, stream>>>(inputs, stats);
  k_wcvt<<<512, 256, 0, stream>>>(Wk, Wv, wbuf);
  k_gemm_kv<<<(Bc * Nc / BM) * 4, 256, 0, stream>>>(inputs, stats, ln_in_g, ln_in_b,
                                                    wbuf, kbuf, vbuf);

  for (int it = 0; it < ITERSc; it++) {
    float* attn = attn_base + (size_t)it * Bc * NSc * Nc;
    k_qproj<<<Bc * NSc, 256, 0, stream>>>(slots, Wq, ln_s_g, ln_s_b, qbuf, Sbuf);
    k_dots<<<Bc * 8, 256, 0, stream>>>(qbuf, (const __hip_bfloat16*)kbuf, attn, Sbuf);
    k_upd_part<<<Bc * 8, 256, 0, stream>>>((const __hip_bfloat16*)vbuf, attn, part);
    k_upd_red<<<Bc * NSc, 256, 0, stream>>>(part, Sbuf, upd);
    k_rel<<<Bc, 256, 0, stream>>>(slots, rel_w1, rel_b1, rel_w2, rel_b2, relb);
    k_gru_ff<<<Bc * NSc, 256, 0, stream>>>(upd, relb, slots,
                                           gru_w_ih, gru_w_hh, gru_b_ih, gru_b_hh,
                                           obj_w1, obj_b1, obj_w2, obj_b2,
                                           ln_ff_g, ln_ff_b,
                                           out, it == ITERSc - 1 ? 1 : 0);
  }
}

// Round 3
// 771.442 us; speedup vs baseline: 3.9434x; 1.6610x over previous
//
#include <hip/hip_runtime.h>
#include <hip/hip_bf16.h>
#include <math.h>

// Problem constants
static constexpr int Bc   = 32;
static constexpr int Nc   = 4096;
static constexpr int Dc   = 256;
static constexpr int NSc  = 8;
static constexpr int HIDc = 128;
static constexpr int ITERSc = 3;
#define EPSf 1e-8f
#define LN_EPSf 1e-5f

typedef __attribute__((ext_vector_type(8))) short bf16x8;
typedef __attribute__((ext_vector_type(8))) unsigned short u16x8;
typedef __attribute__((ext_vector_type(4))) float f32x4;

__device__ __forceinline__ float bf2f(unsigned int u) {
  return __uint_as_float((u & 0xffffu) << 16);
}

__device__ __forceinline__ unsigned short f2bfu(float f) {
  unsigned int u = __float_as_uint(f);
  unsigned int r = (u + 0x7fffu + ((u >> 16) & 1u)) >> 16;
  return (unsigned short)r;
}

__device__ __forceinline__ void bf8_to_f(uint4 r, float* o) {
  o[0] = bf2f(r.x); o[1] = bf2f(r.x >> 16);
  o[2] = bf2f(r.y); o[3] = bf2f(r.y >> 16);
  o[4] = bf2f(r.z); o[5] = bf2f(r.z >> 16);
  o[6] = bf2f(r.w); o[7] = bf2f(r.w >> 16);
}

__device__ __forceinline__ void gl_lds16(const void* g, void* l) {
  __builtin_amdgcn_global_load_lds(
      (__attribute__((address_space(1))) void*)(g),
      (__attribute__((address_space(3))) void*)(l), 16, 0, 0);
}

// block of 256 threads = 4 waves
__device__ __forceinline__ float block_sum(float v, float* tmp) {
  #pragma unroll
  for (int o = 32; o > 0; o >>= 1) v += __shfl_down(v, o, 64);
  int lane = threadIdx.x & 63, wid = threadIdx.x >> 6;
  __syncthreads();
  if (lane == 0) tmp[wid] = v;
  __syncthreads();
  return tmp[0] + tmp[1] + tmp[2] + tmp[3];
}

__device__ __forceinline__ float sigmf(float x) { return 1.f / (1.f + expf(-x)); }

// slots = mu + noise * exp(sigma); 65536 elements
__global__ __launch_bounds__(256) void k_init_slots(const float* __restrict__ noise,
                                                    const float* __restrict__ mu,
                                                    const float* __restrict__ sigma,
                                                    float* __restrict__ slots) {
  int idx = blockIdx.x * 256 + threadIdx.x;
  int d = idx & (Dc - 1);
  slots[idx] = mu[d] + noise[idx] * expf(sigma[d]);
}

// per-row LN stats (mu, rsigma) for inputs; 8 rows per block
__global__ __launch_bounds__(256) void k_stats(const float* __restrict__ inp,
                                               float2* __restrict__ stats) {
  __shared__ float tmp[4];
  int t = threadIdx.x;
  size_t row0 = (size_t)blockIdx.x * 8;
  for (int r = 0; r < 8; r++) {
    float x = inp[(row0 + r) * Dc + t];
    float s = block_sum(x, tmp);
    float m = s * (1.0f / Dc);
    float dx = x - m;
    float s2 = block_sum(dx * dx, tmp);
    float rs = rsqrtf(s2 * (1.0f / Dc) + LN_EPSf);
    if (t == 0) stats[row0 + r] = make_float2(m, rs);
  }
}

// convert Wk (rows 0..255) and Wv (rows 256..511) to bf16 [512][256]
__global__ __launch_bounds__(256) void k_wcvt(const float* __restrict__ Wk,
                                              const float* __restrict__ Wv,
                                              unsigned short* __restrict__ wbuf) {
  int idx = blockIdx.x * 256 + threadIdx.x;  // 0..131071
  int n = idx >> 8, k = idx & 255;
  float v = (n < 256) ? Wk[n * 256 + k] : Wv[(n - 256) * 256 + k];
  wbuf[idx] = f2bfu(v);
}

// build Wcat bf16 [768][768]: row o = [w_ih[o][0:512] | w_hh[o][0:256]]
__global__ __launch_bounds__(256) void k_wprep(const float* __restrict__ w_ih,
                                               const float* __restrict__ w_hh,
                                               unsigned short* __restrict__ Wcat) {
  int idx = blockIdx.x * 256 + threadIdx.x;  // 0..589823
  int o = idx / 768, c = idx - o * 768;
  float v = (c < 512) ? w_ih[o * 512 + c] : w_hh[o * 256 + (c - 512)];
  Wcat[idx] = f2bfu(v);
}

// Fused LN + K/V projection as bf16 MFMA GEMM.
#define BM 128
#define BN 128
#define BK 64
__global__ __launch_bounds__(256) void k_gemm_kv(const float* __restrict__ inp,
                                                 const float2* __restrict__ stats,
                                                 const float* __restrict__ lng,
                                                 const float* __restrict__ lnb,
                                                 const unsigned short* __restrict__ wbuf,
                                                 unsigned short* __restrict__ kbuf,
                                                 unsigned short* __restrict__ vbuf) {
  __shared__ unsigned short Als[BM * BK];
  __shared__ unsigned short Bls[BN * BK];
  int tid = threadIdx.x;
  int lane = tid & 63, w = tid >> 6;
  int idx16 = lane & 15, quad = lane >> 4;
  int m0 = (blockIdx.x >> 2) * BM;
  int n0 = (blockIdx.x & 3) * BN;
  int wm = w & 1, wn = w >> 1;

  f32x4 acc[4][4];
  #pragma unroll
  for (int i = 0; i < 4; i++)
    #pragma unroll
    for (int j = 0; j < 4; j++) acc[i][j] = (f32x4){0.f, 0.f, 0.f, 0.f};

  for (int kt = 0; kt < 4; kt++) {
    int k0 = kt * BK;
    #pragma unroll
    for (int c = 0; c < 4; c++) {
      int idx = (w * 4 + c) * 64 + lane;
      int row = idx >> 3, lc = idx & 7;
      int gc = lc ^ (row & 7);
      const char* gsrc = (const char*)wbuf + ((size_t)(n0 + row) * 256 + k0) * 2 + gc * 16;
      char* ldst = (char*)Bls + (size_t)(w * 4 + c) * 1024;
      gl_lds16(gsrc, ldst);
    }
    #pragma unroll
    for (int p = 0; p < 4; p++) {
      int idx = p * 256 + tid;
      int row = idx >> 3, c8 = idx & 7;
      const float* src = inp + (size_t)(m0 + row) * 256 + k0 + c8 * 8;
      float2 st = stats[m0 + row];
      float4 x0 = *(const float4*)(src);
      float4 x1 = *(const float4*)(src + 4);
      float4 g0 = *(const float4*)(lng + k0 + c8 * 8);
      float4 g1 = *(const float4*)(lng + k0 + c8 * 8 + 4);
      float4 b0 = *(const float4*)(lnb + k0 + c8 * 8);
      float4 b1 = *(const float4*)(lnb + k0 + c8 * 8 + 4);
      u16x8 pk;
      pk[0] = f2bfu((x0.x - st.x) * st.y * g0.x + b0.x);
      pk[1] = f2bfu((x0.y - st.x) * st.y * g0.y + b0.y);
      pk[2] = f2bfu((x0.z - st.x) * st.y * g0.z + b0.z);
      pk[3] = f2bfu((x0.w - st.x) * st.y * g0.w + b0.w);
      pk[4] = f2bfu((x1.x - st.x) * st.y * g1.x + b1.x);
      pk[5] = f2bfu((x1.y - st.x) * st.y * g1.y + b1.y);
      pk[6] = f2bfu((x1.z - st.x) * st.y * g1.z + b1.z);
      pk[7] = f2bfu((x1.w - st.x) * st.y * g1.w + b1.w);
      int dchunk = c8 ^ (row & 7);
      *(u16x8*)((char*)Als + (size_t)(row * 8 + dchunk) * 16) = pk;
    }
    __syncthreads();
    #pragma unroll
    for (int ks = 0; ks < 2; ks++) {
      bf16x8 af[4], bfr[4];
      int kchunk = ks * 4 + quad;
      #pragma unroll
      for (int mt = 0; mt < 4; mt++) {
        int row = wm * 64 + mt * 16 + idx16;
        af[mt] = *(const bf16x8*)((const char*)Als + (size_t)(row * 8 + (kchunk ^ (row & 7))) * 16);
      }
      #pragma unroll
      for (int nt = 0; nt < 4; nt++) {
        int row = wn * 64 + nt * 16 + idx16;
        bfr[nt] = *(const bf16x8*)((const char*)Bls + (size_t)(row * 8 + (kchunk ^ (row & 7))) * 16);
      }
      #pragma unroll
      for (int mt = 0; mt < 4; mt++)
        #pragma unroll
        for (int nt = 0; nt < 4; nt++)
          acc[mt][nt] = __builtin_amdgcn_mfma_f32_16x16x32_bf16(af[mt], bfr[nt], acc[mt][nt], 0, 0, 0);
    }
    __syncthreads();
  }
  unsigned short* dst = (n0 < 256) ? kbuf : vbuf;
  int coff = (n0 < 256) ? n0 : (n0 - 256);
  #pragma unroll
  for (int mt = 0; mt < 4; mt++) {
    #pragma unroll
    for (int nt = 0; nt < 4; nt++) {
      int gm = m0 + wm * 64 + mt * 16 + quad * 4;
      int col = coff + wn * 64 + nt * 16 + idx16;
      #pragma unroll
      for (int r = 0; r < 4; r++)
        dst[(size_t)(gm + r) * 256 + col] = f2bfu(acc[mt][nt][r]);
    }
  }
}

// q = LN(slots) @ Wq^T (one block per slot row); also zero upd row; block 0 zeroes S
__global__ __launch_bounds__(256) void k_qproj0(const float* __restrict__ slots,
                                                const float* __restrict__ Wq,
                                                const float* __restrict__ g,
                                                const float* __restrict__ bb_,
                                                float* __restrict__ q,
                                                float* __restrict__ S,
                                                float* __restrict__ updraw) {
  __shared__ float xs[Dc];
  __shared__ float tmp[4];
  int t = threadIdx.x;
  int row = blockIdx.x;
  updraw[row * 256 + t] = 0.f;
  if (blockIdx.x == 0) S[t] = 0.f;
  float x = slots[row * Dc + t];
  float s = block_sum(x, tmp);
  float m = s * (1.0f / Dc);
  float dx = x - m;
  float s2 = block_sum(dx * dx, tmp);
  float rs = rsqrtf(s2 * (1.0f / Dc) + LN_EPSf);
  xs[t] = dx * rs * g[t] + bb_[t];
  __syncthreads();
  float acc = 0.f;
  const float4* wq4 = (const float4*)(Wq + t * Dc);
  for (int d4 = 0; d4 < Dc / 4; d4++) {
    float4 w = wq4[d4];
    float4 x4 = *(const float4*)&xs[d4 * 4];
    acc += w.x * x4.x + w.y * x4.y + w.z * x4.z + w.w * x4.w;
  }
  q[row * Dc + t] = acc;
}

// Fused dots+softmax+EPS (attn out, S atomics) and PV partial (atomicAdd into updraw).
// grid: 32 b * 8 jc (chunks of 512 tokens)
__global__ __launch_bounds__(256) void k_attn(const float* __restrict__ q,
                                              const unsigned short* __restrict__ kbuf,
                                              const unsigned short* __restrict__ vbuf,
                                              float* __restrict__ attn,
                                              float* __restrict__ S,
                                              float* __restrict__ updraw) {
  __shared__ float qs[NSc][Dc];
  __shared__ float at[NSc][512];
  __shared__ float parts[2][NSc][256];
  __shared__ float tmp[4];
  int t = threadIdx.x;
  int b = blockIdx.x >> 3;
  int jc = blockIdx.x & 7;
  for (int x = t; x < NSc * Dc; x += 256) qs[x >> 8][x & 255] = q[b * NSc * Dc + x];
  __syncthreads();
  int jA = jc * 512 + t;
  const unsigned short* k0 = kbuf + ((size_t)b * Nc + jA) * Dc;
  const unsigned short* k1 = k0 + (size_t)256 * Dc;
  float dot[2][NSc];
  #pragma unroll
  for (int jj = 0; jj < 2; jj++)
    #pragma unroll
    for (int i = 0; i < NSc; i++) dot[jj][i] = 0.f;
  for (int d8 = 0; d8 < Dc / 8; d8++) {
    float kv0[8], kv1[8];
    bf8_to_f(*(const uint4*)(k0 + d8 * 8), kv0);
    bf8_to_f(*(const uint4*)(k1 + d8 * 8), kv1);
    #pragma unroll
    for (int i = 0; i < NSc; i++) {
      const float* qr = &qs[i][d8 * 8];
      float s0 = 0.f, s1 = 0.f;
      #pragma unroll
      for (int u = 0; u < 8; u++) { s0 += kv0[u] * qr[u]; s1 += kv1[u] * qr[u]; }
      dot[0][i] += s0; dot[1][i] += s1;
    }
  }
  float a[2][NSc];
  #pragma unroll
  for (int jj = 0; jj < 2; jj++) {
    float m = -1e30f;
    #pragma unroll
    for (int i = 0; i < NSc; i++) { float s = dot[jj][i] * 0.0625f; dot[jj][i] = s; m = fmaxf(m, s); }
    float sum = 0.f;
    #pragma unroll
    for (int i = 0; i < NSc; i++) { float e = expf(dot[jj][i] - m); a[jj][i] = e; sum += e; }
    float inv = 1.f / sum;
    #pragma unroll
    for (int i = 0; i < NSc; i++) a[jj][i] = a[jj][i] * inv + EPSf;
  }
  float* ab = attn + (size_t)b * NSc * Nc;
  #pragma unroll
  for (int i = 0; i < NSc; i++) {
    ab[i * Nc + jA] = a[0][i];
    ab[i * Nc + jA + 256] = a[1][i];
    at[i][t] = a[0][i];
    at[i][t + 256] = a[1][i];
  }
  for (int i = 0; i < NSc; i++) {
    float bs = block_sum(a[0][i] + a[1][i], tmp);
    if (t == 0) atomicAdd(&S[b * NSc + i], bs);
  }
  __syncthreads();
  // ---- PV phase: rs = wave-pair (row subset), dg = d-group (2 d's/thread) ----
  int rs = t >> 7, dg = t & 127;
  float acc[NSc][2];
  #pragma unroll
  for (int i = 0; i < NSc; i++) { acc[i][0] = 0.f; acc[i][1] = 0.f; }
  const unsigned short* vr = vbuf + ((size_t)b * Nc + jc * 512 + rs * 256) * Dc + dg * 2;
  for (int j = 0; j < 256; j++) {
    unsigned int vv = *(const unsigned int*)(vr + (size_t)j * Dc);
    float v0 = bf2f(vv), v1 = bf2f(vv >> 16);
    #pragma unroll
    for (int i = 0; i < NSc; i++) {
      float a_ = at[i][rs * 256 + j];
      acc[i][0] += a_ * v0;
      acc[i][1] += a_ * v1;
    }
  }
  #pragma unroll
  for (int i = 0; i < NSc; i++) {
    parts[rs][i][dg * 2] = acc[i][0];
    parts[rs][i][dg * 2 + 1] = acc[i][1];
  }
  __syncthreads();
  for (int i = 0; i < NSc; i++) {
    float val = parts[0][i][t] + parts[1][i][t];
    atomicAdd(&updraw[(b * NSc + i) * 256 + t], val);
  }
}

// Relational MLP + X-matrix build. grid 64 (2 blocks/batch, 4 rows each)
__global__ __launch_bounds__(256) void k_slot_a(const float* __restrict__ slots,
                                                const float* __restrict__ updraw,
                                                const float* __restrict__ S,
                                                const float* __restrict__ w1,
                                                const float* __restrict__ b1,
                                                const float* __restrict__ w2,
                                                const float* __restrict__ b2,
                                                unsigned short* __restrict__ Xb) {
  __shared__ float sp[NSc][256];
  __shared__ float xa[4][128];
  __shared__ float xb[NSc][128];
  __shared__ float hs[4][128];
  int t = threadIdx.x;
  int b = blockIdx.x >> 1, half = blockIdx.x & 1;
  int i0 = half * 4;
  for (int x = t; x < NSc * 256; x += 256) sp[x >> 8][x & 255] = slots[b * NSc * 256 + x];
  __syncthreads();
  // upd + slots parts of X for own 4 rows
  for (int r = 0; r < 4; r++) {
    int grow = b * NSc + i0 + r;
    float u = updraw[grow * 256 + t] / S[grow];
    Xb[(size_t)grow * 768 + t] = f2bfu(u);
    Xb[(size_t)grow * 768 + 512 + t] = f2bfu(sp[i0 + r][t]);
  }
  int h = t & 127;
  // xb for all 8 rows
  {
    int jg = t >> 7;
    const float* wr = w1 + h * 512 + 256;
    float acc[4] = {0.f, 0.f, 0.f, 0.f};
    for (int d = 0; d < 256; d += 4) {
      float4 wv = *(const float4*)(wr + d);
      #pragma unroll
      for (int j = 0; j < 4; j++) {
        const float* s4 = &sp[jg * 4 + j][d];
        acc[j] += wv.x * s4[0] + wv.y * s4[1] + wv.z * s4[2] + wv.w * s4[3];
      }
    }
    #pragma unroll
    for (int j = 0; j < 4; j++) xb[jg * 4 + j][h] = acc[j];
  }
  // xa for own 4 rows
  {
    int rg = t >> 7;
    const float* wr = w1 + h * 512;
    float acc[2] = {0.f, 0.f};
    for (int d = 0; d < 256; d += 4) {
      float4 wv = *(const float4*)(wr + d);
      #pragma unroll
      for (int rr = 0; rr < 2; rr++) {
        const float* s4 = &sp[i0 + rg * 2 + rr][d];
        acc[rr] += wv.x * s4[0] + wv.y * s4[1] + wv.z * s4[2] + wv.w * s4[3];
      }
    }
    #pragma unroll
    for (int rr = 0; rr < 2; rr++) xa[rg * 2 + rr][h] = acc[rr];
  }
  __syncthreads();
  // pairwise relu-sum
  {
    float bv = b1[h];
    int ig = t >> 7;
    #pragma unroll
    for (int ii = 0; ii < 2; ii++) {
      int il = ig * 2 + ii;
      int ibatch = i0 + il;
      float av = xa[il][h];
      float s = 0.f;
      #pragma unroll
      for (int j = 0; j < NSc; j++) {
        if (j == ibatch) continue;
        s += fmaxf(av + xb[j][h] + bv, 0.f);
      }
      hs[il][h] = s;
    }
  }
  __syncthreads();
  // msg = hs @ w2^T / 7 + b2 ; write rel part of X
  {
    const float* w2r = w2 + t * 128;
    float acc[4] = {0.f, 0.f, 0.f, 0.f};
    for (int hh = 0; hh < 128; hh += 4) {
      float4 wv = *(const float4*)(w2r + hh);
      #pragma unroll
      for (int r = 0; r < 4; r++) {
        const float* h4 = &hs[r][hh];
        acc[r] += wv.x * h4[0] + wv.y * h4[1] + wv.z * h4[2] + wv.w * h4[3];
      }
    }
    float bv2 = b2[t];
    for (int r = 0; r < 4; r++) {
      float rel = acc[r] * (1.0f / 7.0f) + bv2;
      Xb[(size_t)(b * NSc + i0 + r) * 768 + 256 + t] = f2bfu(rel);
    }
  }
}

// Gates GEMM: Y[256][768] = Xb[256][768] @ Wcat[768][768]^T, bf16 in/out, fp32 acc.
__global__ __launch_bounds__(256) void k_gates(const unsigned short* __restrict__ Xb,
                                               const unsigned short* __restrict__ Wcat,
                                               unsigned short* __restrict__ Yb) {
  __shared__ unsigned short Als[64 * 64];
  __shared__ unsigned short Bls[64 * 64];
  int tid = threadIdx.x;
  int lane = tid & 63, w = tid >> 6;
  int idx16 = lane & 15, quad = lane >> 4;
  int m0 = (blockIdx.x / 12) * 64;
  int n0 = (blockIdx.x % 12) * 64;
  int wm = w & 1, wn = w >> 1;
  f32x4 acc[2][2];
  #pragma unroll
  for (int i = 0; i < 2; i++)
    #pragma unroll
    for (int j = 0; j < 2; j++) acc[i][j] = (f32x4){0.f, 0.f, 0.f, 0.f};

  for (int kt = 0; kt < 12; kt++) {
    int k0 = kt * 64;
    #pragma unroll
    for (int c = 0; c < 2; c++) {
      int idx = (w * 2 + c) * 64 + lane;
      int row = idx >> 3, lc = idx & 7;
      int gc = lc ^ (row & 7);
      gl_lds16((const char*)Xb + (size_t)(m0 + row) * 1536 + k0 * 2 + gc * 16,
               (char*)Als + (size_t)(w * 2 + c) * 1024);
      gl_lds16((const char*)Wcat + (size_t)(n0 + row) * 1536 + k0 * 2 + gc * 16,
               (char*)Bls + (size_t)(w * 2 + c) * 1024);
    }
    __syncthreads();
    #pragma unroll
    for (int ks = 0; ks < 2; ks++) {
      bf16x8 af[2], bfr[2];
      int kchunk = ks * 4 + quad;
      #pragma unroll
      for (int mt = 0; mt < 2; mt++) {
        int row = wm * 32 + mt * 16 + idx16;
        af[mt] = *(const bf16x8*)((const char*)Als + (size_t)(row * 8 + (kchunk ^ (row & 7))) * 16);
      }
      #pragma unroll
      for (int nt = 0; nt < 2; nt++) {
        int row = wn * 32 + nt * 16 + idx16;
        bfr[nt] = *(const bf16x8*)((const char*)Bls + (size_t)(row * 8 + (kchunk ^ (row & 7))) * 16);
      }
      #pragma unroll
      for (int mt = 0; mt < 2; mt++)
        #pragma unroll
        for (int nt = 0; nt < 2; nt++)
          acc[mt][nt] = __builtin_amdgcn_mfma_f32_16x16x32_bf16(af[mt], bfr[nt], acc[mt][nt], 0, 0, 0);
    }
    __syncthreads();
  }
  #pragma unroll
  for (int mt = 0; mt < 2; mt++) {
    #pragma unroll
    for (int nt = 0; nt < 2; nt++) {
      int gm = m0 + wm * 32 + mt * 16 + quad * 4;
      int col = n0 + wn * 32 + nt * 16 + idx16;
      #pragma unroll
      for (int r = 0; r < 4; r++)
        Yb[(size_t)(gm + r) * 768 + col] = f2bfu(acc[mt][nt][r]);
    }
  }
}

// GRU elementwise + LN + FF + residual + next-iter q. grid 64 (4 rows/block)
__global__ __launch_bounds__(256) void k_slot_c(const unsigned short* __restrict__ Yb,
                                                const float* __restrict__ w_hh,
                                                const float* __restrict__ b_ih,
                                                const float* __restrict__ b_hh,
                                                float* __restrict__ slots,
                                                const float* __restrict__ ow1,
                                                const float* __restrict__ ob1,
                                                const float* __restrict__ ow2,
                                                const float* __restrict__ ob2,
                                                const float* __restrict__ lng,
                                                const float* __restrict__ lnb,
                                                const float* __restrict__ lsg,
                                                const float* __restrict__ lsb,
                                                const float* __restrict__ Wq,
                                                float* __restrict__ qbuf,
                                                float* __restrict__ updraw,
                                                float* __restrict__ S,
                                                float* __restrict__ outf,
                                                int wfinal) {
  __shared__ float sp4[4][256];
  __shared__ float ffl[4][256];
  __shared__ float h1l[4][128];
  __shared__ float xs2[4][256];
  __shared__ float tmp[4];
  int t = threadIdx.x;
  int g0 = blockIdx.x * 4;
  for (int x = t; x < 1024; x += 256) sp4[x >> 8][x & 255] = slots[(size_t)g0 * 256 + x];
  __syncthreads();
  // hn_raw (o = t) for 4 rows
  float hn_raw[4] = {0.f, 0.f, 0.f, 0.f};
  {
    const float* whr = w_hh + (size_t)(512 + t) * 256;
    for (int d = 0; d < 256; d += 4) {
      float4 wv = *(const float4*)(whr + d);
      #pragma unroll
      for (int r = 0; r < 4; r++) {
        const float* s4 = &sp4[r][d];
        hn_raw[r] += wv.x * s4[0] + wv.y * s4[1] + wv.z * s4[2] + wv.w * s4[3];
      }
    }
  }
  float bir = b_ih[t], bhr = b_hh[t];
  float biz = b_ih[256 + t], bhz = b_hh[256 + t];
  float bin_ = b_ih[512 + t], bhn = b_hh[512 + t];
  float snew[4];
  #pragma unroll
  for (int r = 0; r < 4; r++) {
    size_t yoff = (size_t)(g0 + r) * 768;
    float yr = bf2f((unsigned int)Yb[yoff + t]);
    float yz = bf2f((unsigned int)Yb[yoff + 256 + t]);
    float yx = bf2f((unsigned int)Yb[yoff + 512 + t]);
    float rg = sigmf(yr + bir + bhr);
    float zg = sigmf(yz + biz + bhz);
    float hn = hn_raw[r] + bhn;
    float xn = (yx - hn_raw[r]) + bin_;
    float ng = tanhf(xn + rg * hn);
    snew[r] = (1.f - zg) * ng + zg * sp4[r][t];
  }
  // LN_ff
  for (int r = 0; r < 4; r++) {
    float s = block_sum(snew[r], tmp);
    float m = s * (1.0f / 256.0f);
    float dx = snew[r] - m;
    float s2 = block_sum(dx * dx, tmp);
    float rs = rsqrtf(s2 * (1.0f / 256.0f) + LN_EPSf);
    ffl[r][t] = dx * rs * lng[t] + lnb[t];
  }
  __syncthreads();
  // h1 = relu(ff @ ow1^T + b1)
  {
    int h = t & 127, rg2 = t >> 7;
    const float* w1r = ow1 + h * 256;
    float acc[2] = {0.f, 0.f};
    for (int d = 0; d < 256; d += 4) {
      float4 wv = *(const float4*)(w1r + d);
      #pragma unroll
      for (int rr = 0; rr < 2; rr++) {
        const float* f4 = &ffl[rg2 * 2 + rr][d];
        acc[rr] += wv.x * f4[0] + wv.y * f4[1] + wv.z * f4[2] + wv.w * f4[3];
      }
    }
    float bo = ob1[h];
    #pragma unroll
    for (int rr = 0; rr < 2; rr++) h1l[rg2 * 2 + rr][h] = fmaxf(acc[rr] + bo, 0.f);
  }
  __syncthreads();
  // out = h1 @ ow2^T + b2 ; residual
  float res[4];
  {
    const float* w2r = ow2 + t * 128;
    float acc[4] = {0.f, 0.f, 0.f, 0.f};
    for (int hh = 0; hh < 128; hh += 4) {
      float4 wv = *(const float4*)(w2r + hh);
      #pragma unroll
      for (int r = 0; r < 4; r++) {
        const float* h4 = &h1l[r][hh];
        acc[r] += wv.x * h4[0] + wv.y * h4[1] + wv.z * h4[2] + wv.w * h4[3];
      }
    }
    float bo2 = ob2[t];
    #pragma unroll
    for (int r = 0; r < 4; r++) res[r] = snew[r] + acc[r] + bo2;
  }
  #pragma unroll
  for (int r = 0; r < 4; r++) {
    slots[(size_t)(g0 + r) * 256 + t] = res[r];
    if (wfinal) outf[(size_t)(g0 + r) * 256 + t] = res[r];
  }
  // q for next iteration: LN_s(res) @ Wq^T
  for (int r = 0; r < 4; r++) {
    float s = block_sum(res[r], tmp);
    float m = s * (1.0f / 256.0f);
    float dx = res[r] - m;
    float s2 = block_sum(dx * dx, tmp);
    float rs = rsqrtf(s2 * (1.0f / 256.0f) + LN_EPSf);
    xs2[r][t] = dx * rs * lsg[t] + lsb[t];
  }
  __syncthreads();
  {
    const float* wqr = Wq + t * 256;
    float acc[4] = {0.f, 0.f, 0.f, 0.f};
    for (int d = 0; d < 256; d += 4) {
      float4 wv = *(const float4*)(wqr + d);
      #pragma unroll
      for (int r = 0; r < 4; r++) {
        const float* x4 = &xs2[r][d];
        acc[r] += wv.x * x4[0] + wv.y * x4[1] + wv.z * x4[2] + wv.w * x4[3];
      }
    }
    #pragma unroll
    for (int r = 0; r < 4; r++) qbuf[(size_t)(g0 + r) * 256 + t] = acc[r];
  }
  // zero accumulators for next iteration
  #pragma unroll
  for (int r = 0; r < 4; r++) updraw[(size_t)(g0 + r) * 256 + t] = 0.f;
  if (t < 4) S[g0 + t] = 0.f;
}

extern "C" void kernel_launch(void* const* d_in, const int* in_sizes, int n_in,
                              void* d_out, int out_size, void* d_ws, size_t ws_size,
                              hipStream_t stream) {
  const float* inputs      = (const float*)d_in[0];
  const float* slot_noise  = (const float*)d_in[1];
  const float* slots_mu    = (const float*)d_in[2];
  const float* slots_sigma = (const float*)d_in[3];
  const float* Wq          = (const float*)d_in[4];
  const float* Wk          = (const float*)d_in[5];
  const float* Wv          = (const float*)d_in[6];
  const float* gru_w_ih    = (const float*)d_in[7];
  const float* gru_w_hh    = (const float*)d_in[8];
  const float* gru_b_ih    = (const float*)d_in[9];
  const float* gru_b_hh    = (const float*)d_in[10];
  const float* obj_w1      = (const float*)d_in[11];
  const float* obj_b1      = (const float*)d_in[12];
  const float* obj_w2      = (const float*)d_in[13];
  const float* obj_b2      = (const float*)d_in[14];
  const float* rel_w1      = (const float*)d_in[15];
  const float* rel_b1      = (const float*)d_in[16];
  const float* rel_w2      = (const float*)d_in[17];
  const float* rel_b2      = (const float*)d_in[18];
  const float* ln_in_g     = (const float*)d_in[19];
  const float* ln_in_b     = (const float*)d_in[20];
  const float* ln_s_g      = (const float*)d_in[21];
  const float* ln_s_b      = (const float*)d_in[22];
  const float* ln_ff_g     = (const float*)d_in[23];
  const float* ln_ff_b     = (const float*)d_in[24];

  // workspace layout (bytes) — total 136,974,336 (< proven 137,364,480):
  //   kbuf bf16 : 0           (+67,108,864)
  //   vbuf bf16 : 67,108,864  (+67,108,864)
  //   qbuf f32  : 134,217,728 (+262,144)
  //   slots f32 : 134,479,872 (+262,144)
  //   updraw f32: 134,742,016 (+262,144)
  //   Sbuf f32  : 135,004,160 (+4,096)
  //   Wcat bf16 : 135,008,256 (+1,179,648)   [stats f32x2 aliases here; dead after gemm_kv,
  //                                           Wcat written by k_wprep AFTER gemm_kv]
  //   Xbuf bf16 : 136,187,904 (+393,216)     [wbuf bf16 (262,144) aliases; dead after gemm_kv]
  //   Ybuf bf16 : 136,581,120 (+393,216)
  char* w = (char*)d_ws;
  unsigned short* kbuf = (unsigned short*)(w);
  unsigned short* vbuf = (unsigned short*)(w + (size_t)67108864);
  float* qbuf   = (float*)(w + (size_t)134217728);
  float* slots  = (float*)(w + (size_t)134479872);
  float* updraw = (float*)(w + (size_t)134742016);
  float* Sbuf   = (float*)(w + (size_t)135004160);
  unsigned short* Wcat = (unsigned short*)(w + (size_t)135008256);
  float2* stats = (float2*)(w + (size_t)135008256);
  unsigned short* Xbuf = (unsigned short*)(w + (size_t)136187904);
  unsigned short* wbuf = (unsigned short*)(w + (size_t)136187904);
  unsigned short* Ybuf = (unsigned short*)(w + (size_t)136581120);

  float* out = (float*)d_out;
  float* attn_base = out + (size_t)Bc * NSc * Dc;

  k_init_slots<<<Bc * NSc * Dc / 256, 256, 0, stream>>>(slot_noise, slots_mu, slots_sigma, slots);
  k_wcvt<<<512, 256, 0, stream>>>(Wk, Wv, wbuf);
  k_stats<<<Bc * Nc / 8, 256, 0, stream>>>(inputs, stats);
  k_gemm_kv<<<(Bc * Nc / BM) * 4, 256, 0, stream>>>(inputs, stats, ln_in_g, ln_in_b,
                                                    wbuf, kbuf, vbuf);
  k_wprep<<<768 * 768 / 256, 256, 0, stream>>>(gru_w_ih, gru_w_hh, Wcat);  // after gemm_kv (aliases stats)
  k_qproj0<<<Bc * NSc, 256, 0, stream>>>(slots, Wq, ln_s_g, ln_s_b, qbuf, Sbuf, updraw);

  for (int it = 0; it < ITERSc; it++) {
    float* attn = attn_base + (size_t)it * Bc * NSc * Nc;
    k_attn<<<Bc * 8, 256, 0, stream>>>(qbuf, kbuf, vbuf, attn, Sbuf, updraw);
    k_slot_a<<<Bc * 2, 256, 0, stream>>>(slots, updraw, Sbuf,
                                         rel_w1, rel_b1, rel_w2, rel_b2, Xbuf);
    k_gates<<<4 * 12, 256, 0, stream>>>(Xbuf, Wcat, Ybuf);
    k_slot_c<<<64, 256, 0, stream>>>(Ybuf, gru_w_hh, gru_b_ih, gru_b_hh, slots,
                                     obj_w1, obj_b1, obj_w2, obj_b2,
                                     ln_ff_g, ln_ff_b, ln_s_g, ln_s_b, Wq,
                                     qbuf, updraw, Sbuf,
                                     out, it == ITERSc - 1 ? 1 : 0);
  }
}

// Round 4
// 692.460 us; speedup vs baseline: 4.3931x; 1.1141x over previous
//
#include <hip/hip_runtime.h>
#include <hip/hip_bf16.h>
#include <math.h>

// Problem constants
static constexpr int Bc   = 32;
static constexpr int Nc   = 4096;
static constexpr int Dc   = 256;
static constexpr int NSc  = 8;
static constexpr int HIDc = 128;
static constexpr int ITERSc = 3;
#define EPSf 1e-8f
#define LN_EPSf 1e-5f

typedef __attribute__((ext_vector_type(8))) short bf16x8;
typedef __attribute__((ext_vector_type(8))) unsigned short u16x8;
typedef __attribute__((ext_vector_type(4))) float f32x4;

// Tw (transposed bf16 weights) element offsets
static constexpr int W1AT = 0;        // [256][128]  rel_w1 A-part^T
static constexpr int W1BT = 32768;    // [256][128]  rel_w1 B-part^T
static constexpr int W2T  = 65536;    // [128][256]  rel_w2^T
static constexpr int OW1T = 98304;    // [256][128]  obj_w1^T
static constexpr int OW2T = 131072;   // [128][256]  obj_w2^T
static constexpr int WQT  = 163840;   // [256][256]  Wq^T
static constexpr int WHNT = 229376;   // [256][256]  w_hh n-part^T
static constexpr int TW_ELEMS = 294912;

__device__ __forceinline__ float bf2f(unsigned int u) {
  return __uint_as_float((u & 0xffffu) << 16);
}

__device__ __forceinline__ unsigned short f2bfu(float f) {
  unsigned int u = __float_as_uint(f);
  unsigned int r = (u + 0x7fffu + ((u >> 16) & 1u)) >> 16;
  return (unsigned short)r;
}

__device__ __forceinline__ void bf8_to_f(uint4 r, float* o) {
  o[0] = bf2f(r.x); o[1] = bf2f(r.x >> 16);
  o[2] = bf2f(r.y); o[3] = bf2f(r.y >> 16);
  o[4] = bf2f(r.z); o[5] = bf2f(r.z >> 16);
  o[6] = bf2f(r.w); o[7] = bf2f(r.w >> 16);
}

__device__ __forceinline__ void gl_lds16(const void* g, void* l) {
  __builtin_amdgcn_global_load_lds(
      (__attribute__((address_space(1))) void*)(g),
      (__attribute__((address_space(3))) void*)(l), 16, 0, 0);
}

__device__ __forceinline__ float block_sum(float v, float* tmp) {
  #pragma unroll
  for (int o = 32; o > 0; o >>= 1) v += __shfl_down(v, o, 64);
  int lane = threadIdx.x & 63, wid = threadIdx.x >> 6;
  __syncthreads();
  if (lane == 0) tmp[wid] = v;
  __syncthreads();
  return tmp[0] + tmp[1] + tmp[2] + tmp[3];
}

__device__ __forceinline__ float sigmf(float x) { return 1.f / (1.f + expf(-x)); }

// slots = mu + noise * exp(sigma)
__global__ __launch_bounds__(256) void k_init_slots(const float* __restrict__ noise,
                                                    const float* __restrict__ mu,
                                                    const float* __restrict__ sigma,
                                                    float* __restrict__ slots) {
  int idx = blockIdx.x * 256 + threadIdx.x;
  int d = idx & (Dc - 1);
  slots[idx] = mu[d] + noise[idx] * expf(sigma[d]);
}

// Wk/Wv -> bf16 [512][256]
__global__ __launch_bounds__(256) void k_wcvt(const float* __restrict__ Wk,
                                              const float* __restrict__ Wv,
                                              unsigned short* __restrict__ wbuf) {
  int idx = blockIdx.x * 256 + threadIdx.x;
  int n = idx >> 8, k = idx & 255;
  float v = (n < 256) ? Wk[n * 256 + k] : Wv[(n - 256) * 256 + k];
  wbuf[idx] = f2bfu(v);
}

// Wcat bf16 [768][768]: rows 0..511: [w_ih | w_hh]; rows 512..767: [w_ih_n | 0]
__global__ __launch_bounds__(256) void k_wprep(const float* __restrict__ w_ih,
                                               const float* __restrict__ w_hh,
                                               unsigned short* __restrict__ Wcat) {
  int idx = blockIdx.x * 256 + threadIdx.x;  // 0..589823
  int o = idx / 768, c = idx - o * 768;
  float v;
  if (c < 512) v = w_ih[o * 512 + c];
  else v = (o < 512) ? w_hh[o * 256 + (c - 512)] : 0.f;
  Wcat[idx] = f2bfu(v);
}

// transposed bf16 weight pack
__global__ __launch_bounds__(256) void k_tprep(const float* __restrict__ rel_w1,
                                               const float* __restrict__ rel_w2,
                                               const float* __restrict__ obj_w1,
                                               const float* __restrict__ obj_w2,
                                               const float* __restrict__ Wq,
                                               const float* __restrict__ w_hh,
                                               unsigned short* __restrict__ Tw) {
  int i = blockIdx.x * 256 + threadIdx.x;
  if (i >= TW_ELEMS) return;
  float v;
  if (i < W1BT) { int j = i - W1AT; int d = j >> 7, h = j & 127; v = rel_w1[h * 512 + d]; }
  else if (i < W2T)  { int j = i - W1BT; int d = j >> 7, h = j & 127; v = rel_w1[h * 512 + 256 + d]; }
  else if (i < OW1T) { int j = i - W2T;  int h = j >> 8, o = j & 255; v = rel_w2[o * 128 + h]; }
  else if (i < OW2T) { int j = i - OW1T; int d = j >> 7, h = j & 127; v = obj_w1[h * 256 + d]; }
  else if (i < WQT)  { int j = i - OW2T; int h = j >> 8, o = j & 255; v = obj_w2[o * 128 + h]; }
  else if (i < WHNT) { int j = i - WQT;  int d = j >> 8, e = j & 255; v = Wq[e * 256 + d]; }
  else               { int j = i - WHNT; int d = j >> 8, o = j & 255; v = w_hh[(512 + o) * 256 + d]; }
  Tw[i] = f2bfu(v);
}

// Fused stats + LN + K/V projection. One block = 64 rows x all 512 cols.
// grid 2048, block 256 (4 waves, wave w covers cols [w*128, w*128+128))
__global__ __launch_bounds__(256, 2) void k_gemm_kv(const float* __restrict__ inp,
                                                    const float* __restrict__ lng,
                                                    const float* __restrict__ lnb,
                                                    const unsigned short* __restrict__ wbuf,
                                                    unsigned short* __restrict__ kbuf,
                                                    unsigned short* __restrict__ vbuf) {
  __shared__ unsigned short Als[64 * 64];   // 8 KB, xor-swizzled 16B chunks
  __shared__ unsigned short Bls[512 * 64];  // 64 KB
  __shared__ float smu[64];
  __shared__ float srs[64];
  int tid = threadIdx.x;
  int lane = tid & 63, w = tid >> 6;
  int idx16 = lane & 15, quad = lane >> 4;
  int m0 = blockIdx.x * 64;

  // ---- pass 1: per-row LN stats (wave w handles rows w*16 .. w*16+15) ----
  for (int rr = 0; rr < 16; rr++) {
    int row = w * 16 + rr;
    float4 v = *(const float4*)(inp + (size_t)(m0 + row) * 256 + lane * 4);
    float s = v.x + v.y + v.z + v.w;
    float q = v.x * v.x + v.y * v.y + v.z * v.z + v.w * v.w;
    #pragma unroll
    for (int o = 32; o > 0; o >>= 1) { s += __shfl_down(s, o, 64); q += __shfl_down(q, o, 64); }
    if (lane == 0) {
      float mu = s * (1.0f / 256.0f);
      float var = q * (1.0f / 256.0f) - mu * mu;
      smu[row] = mu;
      srs[row] = rsqrtf(var + LN_EPSf);
    }
  }
  __syncthreads();

  f32x4 acc[4][8];
  #pragma unroll
  for (int i = 0; i < 4; i++)
    #pragma unroll
    for (int j = 0; j < 8; j++) acc[i][j] = (f32x4){0.f, 0.f, 0.f, 0.f};

  for (int kt = 0; kt < 4; kt++) {
    int k0 = kt * 64;
    // stage B (512x64) via async global->LDS, 16 chunks/thread
    #pragma unroll
    for (int c = 0; c < 16; c++) {
      int idx = (w * 16 + c) * 64 + lane;
      int row = idx >> 3, lc = idx & 7;
      int gc = lc ^ (row & 7);
      gl_lds16((const char*)wbuf + ((size_t)row * 256 + k0) * 2 + gc * 16,
               (char*)Bls + (size_t)(w * 16 + c) * 1024);
    }
    // stage A (64x64): fp32 load + LN + bf16 pack, 2 chunks/thread
    #pragma unroll
    for (int p = 0; p < 2; p++) {
      int idx = p * 256 + tid;
      int row = idx >> 3, c8 = idx & 7;
      const float* src = inp + (size_t)(m0 + row) * 256 + k0 + c8 * 8;
      float mu = smu[row], rs = srs[row];
      float4 x0 = *(const float4*)(src);
      float4 x1 = *(const float4*)(src + 4);
      float4 g0 = *(const float4*)(lng + k0 + c8 * 8);
      float4 g1 = *(const float4*)(lng + k0 + c8 * 8 + 4);
      float4 b0 = *(const float4*)(lnb + k0 + c8 * 8);
      float4 b1 = *(const float4*)(lnb + k0 + c8 * 8 + 4);
      u16x8 pk;
      pk[0] = f2bfu((x0.x - mu) * rs * g0.x + b0.x);
      pk[1] = f2bfu((x0.y - mu) * rs * g0.y + b0.y);
      pk[2] = f2bfu((x0.z - mu) * rs * g0.z + b0.z);
      pk[3] = f2bfu((x0.w - mu) * rs * g0.w + b0.w);
      pk[4] = f2bfu((x1.x - mu) * rs * g1.x + b1.x);
      pk[5] = f2bfu((x1.y - mu) * rs * g1.y + b1.y);
      pk[6] = f2bfu((x1.z - mu) * rs * g1.z + b1.z);
      pk[7] = f2bfu((x1.w - mu) * rs * g1.w + b1.w);
      int dchunk = c8 ^ (row & 7);
      *(u16x8*)((char*)Als + (size_t)(row * 8 + dchunk) * 16) = pk;
    }
    __syncthreads();
    #pragma unroll
    for (int ks = 0; ks < 2; ks++) {
      int kchunk = ks * 4 + quad;
      bf16x8 af[4], bfr[8];
      #pragma unroll
      for (int mt = 0; mt < 4; mt++) {
        int row = mt * 16 + idx16;
        af[mt] = *(const bf16x8*)((const char*)Als + (size_t)(row * 8 + (kchunk ^ (row & 7))) * 16);
      }
      #pragma unroll
      for (int nt = 0; nt < 8; nt++) {
        int row = w * 128 + nt * 16 + idx16;
        bfr[nt] = *(const bf16x8*)((const char*)Bls + (size_t)(row * 8 + (kchunk ^ (row & 7))) * 16);
      }
      #pragma unroll
      for (int mt = 0; mt < 4; mt++)
        #pragma unroll
        for (int nt = 0; nt < 8; nt++)
          acc[mt][nt] = __builtin_amdgcn_mfma_f32_16x16x32_bf16(af[mt], bfr[nt], acc[mt][nt], 0, 0, 0);
    }
    __syncthreads();
  }
  // epilogue: C/D layout col=lane&15, row=quad*4+reg
  #pragma unroll
  for (int mt = 0; mt < 4; mt++) {
    #pragma unroll
    for (int nt = 0; nt < 8; nt++) {
      int gm = m0 + mt * 16 + quad * 4;
      int col = w * 128 + nt * 16 + idx16;
      unsigned short* dst = (col < 256) ? kbuf : vbuf;
      int c = col & 255;
      #pragma unroll
      for (int r = 0; r < 4; r++)
        dst[(size_t)(gm + r) * 256 + c] = f2bfu(acc[mt][nt][r]);
    }
  }
}

// q = LN(slots) @ Wq^T (bf16 out); zero updraw + S. grid 256 (one slot row/block)
__global__ __launch_bounds__(256) void k_qproj0(const float* __restrict__ slots,
                                                const unsigned short* __restrict__ Tw,
                                                const float* __restrict__ g,
                                                const float* __restrict__ bb_,
                                                unsigned short* __restrict__ qb,
                                                float* __restrict__ S,
                                                float* __restrict__ updraw) {
  __shared__ float xs[Dc];
  __shared__ float tmp[4];
  int t = threadIdx.x;
  int row = blockIdx.x;
  updraw[row * 256 + t] = 0.f;
  if (blockIdx.x == 0) S[t] = 0.f;
  float x = slots[row * Dc + t];
  float s = block_sum(x, tmp);
  float m = s * (1.0f / Dc);
  float dx = x - m;
  float s2 = block_sum(dx * dx, tmp);
  float rs = rsqrtf(s2 * (1.0f / Dc) + LN_EPSf);
  xs[t] = dx * rs * g[t] + bb_[t];
  __syncthreads();
  float acc = 0.f;
  const unsigned short* wq = Tw + WQT;
  for (int d = 0; d < 256; d++) acc += bf2f(wq[d * 256 + t]) * xs[d];
  qb[row * 256 + t] = f2bfu(acc);
}

// Fused dots+softmax+EPS + PV partial. grid 32 b * 16 jc (256 tokens each)
__global__ __launch_bounds__(256) void k_attn(const unsigned short* __restrict__ qb,
                                              const unsigned short* __restrict__ kbuf,
                                              const unsigned short* __restrict__ vbuf,
                                              float* __restrict__ attn,
                                              float* __restrict__ S,
                                              float* __restrict__ updraw) {
  __shared__ float qs[NSc][Dc];
  __shared__ float at[NSc][256];
  __shared__ float parts[2][NSc][256];
  int t = threadIdx.x;
  int b = blockIdx.x >> 4;
  int jc = blockIdx.x & 15;
  int j0 = jc * 256;
  for (int x = t; x < NSc * Dc; x += 256) qs[x >> 8][x & 255] = bf2f(qb[b * NSc * Dc + x]);
  __syncthreads();
  int j = j0 + t;
  const uint4* krow = (const uint4*)(kbuf + ((size_t)b * Nc + j) * Dc);
  float dot[NSc];
  #pragma unroll
  for (int i = 0; i < NSc; i++) dot[i] = 0.f;
  for (int d8 = 0; d8 < Dc / 8; d8++) {
    float kv[8];
    bf8_to_f(krow[d8], kv);
    #pragma unroll
    for (int i = 0; i < NSc; i++) {
      const float* qr = &qs[i][d8 * 8];
      float s0 = 0.f;
      #pragma unroll
      for (int u = 0; u < 8; u++) s0 += kv[u] * qr[u];
      dot[i] += s0;
    }
  }
  float m = -1e30f;
  #pragma unroll
  for (int i = 0; i < NSc; i++) { float s = dot[i] * 0.0625f; dot[i] = s; m = fmaxf(m, s); }
  float sum = 0.f;
  float a[NSc];
  #pragma unroll
  for (int i = 0; i < NSc; i++) { float e = expf(dot[i] - m); a[i] = e; sum += e; }
  float inv = 1.f / sum;
  #pragma unroll
  for (int i = 0; i < NSc; i++) a[i] = a[i] * inv + EPSf;
  float* ab = attn + (size_t)b * NSc * Nc;
  #pragma unroll
  for (int i = 0; i < NSc; i++) {
    ab[i * Nc + j] = a[i];
    at[i][t] = a[i];
  }
  __syncthreads();
  // S reduction: wave w handles slots w and w+4
  {
    int wv = t >> 6, lane = t & 63;
    #pragma unroll
    for (int ii = 0; ii < 2; ii++) {
      int i = wv + ii * 4;
      float4 v = *(const float4*)&at[i][lane * 4];
      float s = v.x + v.y + v.z + v.w;
      #pragma unroll
      for (int o = 32; o > 0; o >>= 1) s += __shfl_down(s, o, 64);
      if (lane == 0) atomicAdd(&S[b * NSc + i], s);
    }
  }
  // PV: rs = token-half, dg = d-pair
  int rsh = t >> 7, dg = t & 127;
  float acc[NSc][2];
  #pragma unroll
  for (int i = 0; i < NSc; i++) { acc[i][0] = 0.f; acc[i][1] = 0.f; }
  const unsigned short* vr = vbuf + ((size_t)b * Nc + j0 + rsh * 128) * Dc + dg * 2;
  for (int jj = 0; jj < 128; jj += 2) {
    unsigned int v0 = *(const unsigned int*)(vr + (size_t)jj * Dc);
    unsigned int v1 = *(const unsigned int*)(vr + (size_t)(jj + 1) * Dc);
    float v0a = bf2f(v0), v0b = bf2f(v0 >> 16);
    float v1a = bf2f(v1), v1b = bf2f(v1 >> 16);
    #pragma unroll
    for (int i = 0; i < NSc; i++) {
      float2 ap = *(const float2*)&at[i][rsh * 128 + jj];
      acc[i][0] += ap.x * v0a + ap.y * v1a;
      acc[i][1] += ap.x * v0b + ap.y * v1b;
    }
  }
  #pragma unroll
  for (int i = 0; i < NSc; i++) {
    parts[rsh][i][dg * 2] = acc[i][0];
    parts[rsh][i][dg * 2 + 1] = acc[i][1];
  }
  __syncthreads();
  for (int i = 0; i < NSc; i++) {
    float val = parts[0][i][t] + parts[1][i][t];
    atomicAdd(&updraw[(b * NSc + i) * 256 + t], val);
  }
}

// Relational MLP + X build. grid 64 (2 blocks/batch, 4 rows each)
__global__ __launch_bounds__(256) void k_slot_a(const float* __restrict__ slots,
                                                const float* __restrict__ updraw,
                                                const float* __restrict__ S,
                                                const unsigned short* __restrict__ Tw,
                                                const float* __restrict__ b1,
                                                const float* __restrict__ b2,
                                                unsigned short* __restrict__ Xb) {
  __shared__ float sp[NSc][256];
  __shared__ float xpart[2][12][128];
  __shared__ float xabl[12][128];   // 0..7 = xb rows, 8..11 = xa (own rows)
  __shared__ float hs[4][128];
  int t = threadIdx.x;
  int b = blockIdx.x >> 1, half = blockIdx.x & 1;
  int i0 = half * 4;
  for (int x = t; x < NSc * 256; x += 256) sp[x >> 8][x & 255] = slots[b * NSc * 256 + x];
  __syncthreads();
  for (int r = 0; r < 4; r++) {
    int grow = b * NSc + i0 + r;
    float u = updraw[grow * 256 + t] / S[grow];
    Xb[(size_t)grow * 768 + t] = f2bfu(u);
    Xb[(size_t)grow * 768 + 512 + t] = f2bfu(sp[i0 + r][t]);
  }
  int h = t & 127, dh = t >> 7;
  {
    const unsigned short* wa = Tw + W1AT;
    const unsigned short* wb = Tw + W1BT;
    float accb[8] = {0, 0, 0, 0, 0, 0, 0, 0};
    float acca[4] = {0, 0, 0, 0};
    for (int dd = 0; dd < 128; dd++) {
      int d = dh * 128 + dd;
      float wbv = bf2f(wb[d * 128 + h]);
      float wav = bf2f(wa[d * 128 + h]);
      #pragma unroll
      for (int jj = 0; jj < 8; jj++) accb[jj] += wbv * sp[jj][d];
      #pragma unroll
      for (int r = 0; r < 4; r++) acca[r] += wav * sp[i0 + r][d];
    }
    #pragma unroll
    for (int jj = 0; jj < 8; jj++) xpart[dh][jj][h] = accb[jj];
    #pragma unroll
    for (int r = 0; r < 4; r++) xpart[dh][8 + r][h] = acca[r];
  }
  __syncthreads();
  {
    int g = t >> 7;
    for (int jj = g * 6; jj < g * 6 + 6; jj++)
      xabl[jj][h] = xpart[0][jj][h] + xpart[1][jj][h];
  }
  __syncthreads();
  {
    float bv = b1[h];
    int ig = t >> 7;
    #pragma unroll
    for (int ii = 0; ii < 2; ii++) {
      int il = ig * 2 + ii;
      int ibatch = i0 + il;
      float av = xabl[8 + il][h];
      float s = 0.f;
      #pragma unroll
      for (int jj = 0; jj < NSc; jj++) {
        if (jj == ibatch) continue;
        s += fmaxf(av + xabl[jj][h] + bv, 0.f);
      }
      hs[il][h] = s;
    }
  }
  __syncthreads();
  {
    const unsigned short* w2 = Tw + W2T;
    float am[4] = {0, 0, 0, 0};
    for (int hh = 0; hh < 128; hh++) {
      float wv = bf2f(w2[hh * 256 + t]);
      #pragma unroll
      for (int r = 0; r < 4; r++) am[r] += wv * hs[r][hh];
    }
    float bv2 = b2[t];
    for (int r = 0; r < 4; r++) {
      float rel = am[r] * (1.0f / 7.0f) + bv2;
      Xb[(size_t)(b * NSc + i0 + r) * 768 + 256 + t] = f2bfu(rel);
    }
  }
}

// Gates GEMM: Y[256][768] = Xb @ Wcat^T (bf16, fp32 acc). grid 48
__global__ __launch_bounds__(256) void k_gates(const unsigned short* __restrict__ Xb,
                                               const unsigned short* __restrict__ Wcat,
                                               unsigned short* __restrict__ Yb) {
  __shared__ unsigned short Als[64 * 64];
  __shared__ unsigned short Bls[64 * 64];
  int tid = threadIdx.x;
  int lane = tid & 63, w = tid >> 6;
  int idx16 = lane & 15, quad = lane >> 4;
  int m0 = (blockIdx.x / 12) * 64;
  int n0 = (blockIdx.x % 12) * 64;
  int wm = w & 1, wn = w >> 1;
  f32x4 acc[2][2];
  #pragma unroll
  for (int i = 0; i < 2; i++)
    #pragma unroll
    for (int j = 0; j < 2; j++) acc[i][j] = (f32x4){0.f, 0.f, 0.f, 0.f};

  for (int kt = 0; kt < 12; kt++) {
    int k0 = kt * 64;
    #pragma unroll
    for (int c = 0; c < 2; c++) {
      int idx = (w * 2 + c) * 64 + lane;
      int row = idx >> 3, lc = idx & 7;
      int gc = lc ^ (row & 7);
      gl_lds16((const char*)Xb + (size_t)(m0 + row) * 1536 + k0 * 2 + gc * 16,
               (char*)Als + (size_t)(w * 2 + c) * 1024);
      gl_lds16((const char*)Wcat + (size_t)(n0 + row) * 1536 + k0 * 2 + gc * 16,
               (char*)Bls + (size_t)(w * 2 + c) * 1024);
    }
    __syncthreads();
    #pragma unroll
    for (int ks = 0; ks < 2; ks++) {
      bf16x8 af[2], bfr[2];
      int kchunk = ks * 4 + quad;
      #pragma unroll
      for (int mt = 0; mt < 2; mt++) {
        int row = wm * 32 + mt * 16 + idx16;
        af[mt] = *(const bf16x8*)((const char*)Als + (size_t)(row * 8 + (kchunk ^ (row & 7))) * 16);
      }
      #pragma unroll
      for (int nt = 0; nt < 2; nt++) {
        int row = wn * 32 + nt * 16 + idx16;
        bfr[nt] = *(const bf16x8*)((const char*)Bls + (size_t)(row * 8 + (kchunk ^ (row & 7))) * 16);
      }
      #pragma unroll
      for (int mt = 0; mt < 2; mt++)
        #pragma unroll
        for (int nt = 0; nt < 2; nt++)
          acc[mt][nt] = __builtin_amdgcn_mfma_f32_16x16x32_bf16(af[mt], bfr[nt], acc[mt][nt], 0, 0, 0);
    }
    __syncthreads();
  }
  #pragma unroll
  for (int mt = 0; mt < 2; mt++) {
    #pragma unroll
    for (int nt = 0; nt < 2; nt++) {
      int gm = m0 + wm * 32 + mt * 16 + quad * 4;
      int col = n0 + wn * 32 + nt * 16 + idx16;
      #pragma unroll
      for (int r = 0; r < 4; r++)
        Yb[(size_t)(gm + r) * 768 + col] = f2bfu(acc[mt][nt][r]);
    }
  }
}

// GRU elementwise + LN + FF + residual + next-iter q. grid 64 (4 rows/block)
__global__ __launch_bounds__(256) void k_slot_c(const unsigned short* __restrict__ Yb,
                                                const unsigned short* __restrict__ Tw,
                                                const float* __restrict__ b_ih,
                                                const float* __restrict__ b_hh,
                                                float* __restrict__ slots,
                                                const float* __restrict__ ob1,
                                                const float* __restrict__ ob2,
                                                const float* __restrict__ lng,
                                                const float* __restrict__ lnb,
                                                const float* __restrict__ lsg,
                                                const float* __restrict__ lsb,
                                                unsigned short* __restrict__ qb,
                                                float* __restrict__ updraw,
                                                float* __restrict__ S,
                                                float* __restrict__ outf,
                                                int wfinal) {
  __shared__ float sp4[4][256];
  __shared__ float ffl[4][256];
  __shared__ float h1p[2][4][128];
  __shared__ float h1l[4][128];
  __shared__ float xs2[4][256];
  int t = threadIdx.x;
  int g0 = blockIdx.x * 4;
  for (int x = t; x < 1024; x += 256) sp4[x >> 8][x & 255] = slots[(size_t)g0 * 256 + x];
  __syncthreads();
  // hn_raw via whnT (coalesced); o = t
  float hn[4] = {0, 0, 0, 0};
  {
    const unsigned short* wh = Tw + WHNT;
    for (int d = 0; d < 256; d++) {
      float wv = bf2f(wh[d * 256 + t]);
      #pragma unroll
      for (int r = 0; r < 4; r++) hn[r] += wv * sp4[r][d];
    }
  }
  float bir = b_ih[t], bhr = b_hh[t];
  float biz = b_ih[256 + t], bhz = b_hh[256 + t];
  float bin_ = b_ih[512 + t], bhn = b_hh[512 + t];
  float snew[4];
  #pragma unroll
  for (int r = 0; r < 4; r++) {
    size_t yoff = (size_t)(g0 + r) * 768;
    float yr = bf2f((unsigned int)Yb[yoff + t]);
    float yz = bf2f((unsigned int)Yb[yoff + 256 + t]);
    float yx = bf2f((unsigned int)Yb[yoff + 512 + t]);
    float rg = sigmf(yr + bir + bhr);
    float zg = sigmf(yz + biz + bhz);
    float ng = tanhf(yx + bin_ + rg * (hn[r] + bhn));
    snew[r] = (1.f - zg) * ng + zg * sp4[r][t];
    ffl[r][t] = snew[r];
  }
  __syncthreads();
  // wave-per-row LN_ff
  {
    int wv = t >> 6, lane = t & 63;
    float4 v = *(const float4*)&ffl[wv][lane * 4];
    float s = v.x + v.y + v.z + v.w;
    float q = v.x * v.x + v.y * v.y + v.z * v.z + v.w * v.w;
    #pragma unroll
    for (int o = 32; o > 0; o >>= 1) { s += __shfl_down(s, o, 64); q += __shfl_down(q, o, 64); }
    s = __shfl(s, 0, 64); q = __shfl(q, 0, 64);
    float mu = s * (1.0f / 256.0f);
    float rs = rsqrtf(q * (1.0f / 256.0f) - mu * mu + LN_EPSf);
    float4 g4 = *(const float4*)&lng[lane * 4];
    float4 b4 = *(const float4*)&lnb[lane * 4];
    float4 o4;
    o4.x = (v.x - mu) * rs * g4.x + b4.x;
    o4.y = (v.y - mu) * rs * g4.y + b4.y;
    o4.z = (v.z - mu) * rs * g4.z + b4.z;
    o4.w = (v.w - mu) * rs * g4.w + b4.w;
    *(float4*)&ffl[wv][lane * 4] = o4;
  }
  __syncthreads();
  // h1 = relu(ff @ ow1^T + b1), d-split halves
  {
    const unsigned short* w1 = Tw + OW1T;
    int h = t & 127, dh = t >> 7;
    float a1[4] = {0, 0, 0, 0};
    for (int dd = 0; dd < 128; dd++) {
      int d = dh * 128 + dd;
      float wv = bf2f(w1[d * 128 + h]);
      #pragma unroll
      for (int r = 0; r < 4; r++) a1[r] += wv * ffl[r][d];
    }
    #pragma unroll
    for (int r = 0; r < 4; r++) h1p[dh][r][h] = a1[r];
  }
  __syncthreads();
  {
    int h = t & 127, g = t >> 7;
    float bo = ob1[h];
    #pragma unroll
    for (int rr = 0; rr < 2; rr++) {
      int r = g * 2 + rr;
      h1l[r][h] = fmaxf(h1p[0][r][h] + h1p[1][r][h] + bo, 0.f);
    }
  }
  __syncthreads();
  float res[4];
  {
    const unsigned short* w2 = Tw + OW2T;
    float ao[4] = {0, 0, 0, 0};
    for (int hh = 0; hh < 128; hh++) {
      float wv = bf2f(w2[hh * 256 + t]);
      #pragma unroll
      for (int r = 0; r < 4; r++) ao[r] += wv * h1l[r][hh];
    }
    float bo2 = ob2[t];
    #pragma unroll
    for (int r = 0; r < 4; r++) res[r] = snew[r] + ao[r] + bo2;
  }
  #pragma unroll
  for (int r = 0; r < 4; r++) {
    slots[(size_t)(g0 + r) * 256 + t] = res[r];
    if (wfinal) outf[(size_t)(g0 + r) * 256 + t] = res[r];
    xs2[r][t] = res[r];
  }
  __syncthreads();
  // wave-per-row LN_s
  {
    int wv = t >> 6, lane = t & 63;
    float4 v = *(const float4*)&xs2[wv][lane * 4];
    float s = v.x + v.y + v.z + v.w;
    float q = v.x * v.x + v.y * v.y + v.z * v.z + v.w * v.w;
    #pragma unroll
    for (int o = 32; o > 0; o >>= 1) { s += __shfl_down(s, o, 64); q += __shfl_down(q, o, 64); }
    s = __shfl(s, 0, 64); q = __shfl(q, 0, 64);
    float mu = s * (1.0f / 256.0f);
    float rs = rsqrtf(q * (1.0f / 256.0f) - mu * mu + LN_EPSf);
    float4 g4 = *(const float4*)&lsg[lane * 4];
    float4 b4 = *(const float4*)&lsb[lane * 4];
    float4 o4;
    o4.x = (v.x - mu) * rs * g4.x + b4.x;
    o4.y = (v.y - mu) * rs * g4.y + b4.y;
    o4.z = (v.z - mu) * rs * g4.z + b4.z;
    o4.w = (v.w - mu) * rs * g4.w + b4.w;
    *(float4*)&xs2[wv][lane * 4] = o4;
  }
  __syncthreads();
  // q = LN_s(res) @ Wq^T
  {
    const unsigned short* wq = Tw + WQT;
    float aq[4] = {0, 0, 0, 0};
    for (int d = 0; d < 256; d++) {
      float wv = bf2f(wq[d * 256 + t]);
      #pragma unroll
      for (int r = 0; r < 4; r++) aq[r] += wv * xs2[r][d];
    }
    #pragma unroll
    for (int r = 0; r < 4; r++) qb[(size_t)(g0 + r) * 256 + t] = f2bfu(aq[r]);
  }
  #pragma unroll
  for (int r = 0; r < 4; r++) updraw[(size_t)(g0 + r) * 256 + t] = 0.f;
  if (t < 4) S[g0 + t] = 0.f;
}

extern "C" void kernel_launch(void* const* d_in, const int* in_sizes, int n_in,
                              void* d_out, int out_size, void* d_ws, size_t ws_size,
                              hipStream_t stream) {
  const float* inputs      = (const float*)d_in[0];
  const float* slot_noise  = (const float*)d_in[1];
  const float* slots_mu    = (const float*)d_in[2];
  const float* slots_sigma = (const float*)d_in[3];
  const float* Wq          = (const float*)d_in[4];
  const float* Wk          = (const float*)d_in[5];
  const float* Wv          = (const float*)d_in[6];
  const float* gru_w_ih    = (const float*)d_in[7];
  const float* gru_w_hh    = (const float*)d_in[8];
  const float* gru_b_ih    = (const float*)d_in[9];
  const float* gru_b_hh    = (const float*)d_in[10];
  const float* obj_w1      = (const float*)d_in[11];
  const float* obj_b1      = (const float*)d_in[12];
  const float* obj_w2      = (const float*)d_in[13];
  const float* obj_b2      = (const float*)d_in[14];
  const float* rel_w1      = (const float*)d_in[15];
  const float* rel_b1      = (const float*)d_in[16];
  const float* rel_w2      = (const float*)d_in[17];
  const float* rel_b2      = (const float*)d_in[18];
  const float* ln_in_g     = (const float*)d_in[19];
  const float* ln_in_b     = (const float*)d_in[20];
  const float* ln_s_g      = (const float*)d_in[21];
  const float* ln_s_b      = (const float*)d_in[22];
  const float* ln_ff_g     = (const float*)d_in[23];
  const float* ln_ff_b     = (const float*)d_in[24];

  // workspace layout (bytes), total 137,298,944 <= proven 137,364,480:
  //   kbuf bf16  : 0           (+67,108,864)
  //   vbuf bf16  : 67,108,864  (+67,108,864)
  //   slots f32  : 134,217,728 (+262,144)
  //   updraw f32 : 134,479,872 (+262,144)
  //   Sbuf f32   : 134,742,016 (+1,024)
  //   Wcat bf16  : 134,743,040 (+1,179,648)
  //   Tw bf16    : 135,922,688 (+589,824)
  //   Xbuf bf16  : 136,512,512 (+393,216)  [qb bf16 (131,072) aliases head: safe —
  //                                         attn consumes q before slot_a rewrites X;
  //                                         slot_c writes q after gates consumed X]
  //   Ybuf bf16  : 136,905,728 (+393,216)  [wbuf bf16 (262,144) aliases: dead after gemm]
  char* w = (char*)d_ws;
  unsigned short* kbuf = (unsigned short*)(w);
  unsigned short* vbuf = (unsigned short*)(w + (size_t)67108864);
  float* slots  = (float*)(w + (size_t)134217728);
  float* updraw = (float*)(w + (size_t)134479872);
  float* Sbuf   = (float*)(w + (size_t)134742016);
  unsigned short* Wcat = (unsigned short*)(w + (size_t)134743040);
  unsigned short* Tw   = (unsigned short*)(w + (size_t)135922688);
  unsigned short* Xbuf = (unsigned short*)(w + (size_t)136512512);
  unsigned short* qb   = (unsigned short*)(w + (size_t)136512512);
  unsigned short* Ybuf = (unsigned short*)(w + (size_t)136905728);
  unsigned short* wbuf = (unsigned short*)(w + (size_t)136905728);

  float* out = (float*)d_out;
  float* attn_base = out + (size_t)Bc * NSc * Dc;

  k_init_slots<<<Bc * NSc * Dc / 256, 256, 0, stream>>>(slot_noise, slots_mu, slots_sigma, slots);
  k_wcvt<<<512, 256, 0, stream>>>(Wk, Wv, wbuf);
  k_wprep<<<768 * 768 / 256, 256, 0, stream>>>(gru_w_ih, gru_w_hh, Wcat);
  k_tprep<<<(TW_ELEMS + 255) / 256, 256, 0, stream>>>(rel_w1, rel_w2, obj_w1, obj_w2, Wq, gru_w_hh, Tw);
  k_gemm_kv<<<Bc * Nc / 64, 256, 0, stream>>>(inputs, ln_in_g, ln_in_b, wbuf, kbuf, vbuf);
  k_qproj0<<<Bc * NSc, 256, 0, stream>>>(slots, Tw, ln_s_g, ln_s_b, qb, Sbuf, updraw);

  for (int it = 0; it < ITERSc; it++) {
    float* attn = attn_base + (size_t)it * Bc * NSc * Nc;
    k_attn<<<Bc * 16, 256, 0, stream>>>(qb, kbuf, vbuf, attn, Sbuf, updraw);
    k_slot_a<<<Bc * 2, 256, 0, stream>>>(slots, updraw, Sbuf, Tw, rel_b1, rel_b2, Xbuf);
    k_gates<<<4 * 12, 256, 0, stream>>>(Xbuf, Wcat, Ybuf);
    k_slot_c<<<64, 256, 0, stream>>>(Ybuf, Tw, gru_b_ih, gru_b_hh, slots,
                                     obj_b1, obj_b2, ln_ff_g, ln_ff_b, ln_s_g, ln_s_b,
                                     qb, updraw, Sbuf,
                                     out, it == ITERSc - 1 ? 1 : 0);
  }
}